// Round 9
// baseline (258.668 us; speedup 1.0000x reference)
//
#include <hip/hip_runtime.h>
#include <math.h>

#define B_    4
#define SEQ_  2048
#define S_    128
#define L_    2304          // SEQ + 2*S
#define DIN   512
#define DK    64
#define NEGINF (-1e30f)
#define SCALE 0.125f
#define NCOLS 2176          // start(128) + mid(2048) key columns
#define NMID  8192          // B_*SEQ_
#define NEDGE 1024          // B_*2*S_
#define LE    2304          // edge D row length

typedef _Float16 f16;
typedef __attribute__((ext_vector_type(8))) _Float16 half8;
typedef __attribute__((ext_vector_type(4))) float f32x4;

// ---------------------------------------------------------------------------
// k_ln: wave-per-row LayerNorm, writes hi/lo fp16 split of xn.
// ---------------------------------------------------------------------------
__global__ __launch_bounds__(256) void k_ln(
    const float* __restrict__ x,
    const float* __restrict__ g0, const float* __restrict__ b0,
    const float* __restrict__ gs, const float* __restrict__ bs,
    const float* __restrict__ ge, const float* __restrict__ be,
    f16* __restrict__ xh, f16* __restrict__ xl)
{
    const int wave = threadIdx.x >> 6, lane = threadIdx.x & 63;
    const int row  = blockIdx.x * 4 + wave;
    const float4* xr = (const float4*)(x + (size_t)row * DIN);
    float4 v0 = xr[lane], v1 = xr[lane + 64];
    float s  = v0.x + v0.y + v0.z + v0.w + v1.x + v1.y + v1.z + v1.w;
    float s2 = v0.x*v0.x + v0.y*v0.y + v0.z*v0.z + v0.w*v0.w
             + v1.x*v1.x + v1.y*v1.y + v1.z*v1.z + v1.w*v1.w;
    #pragma unroll
    for (int m = 1; m < 64; m <<= 1) { s += __shfl_xor(s, m); s2 += __shfl_xor(s2, m); }
    float mean = s * (1.f / DIN);
    float var  = s2 * (1.f / DIN) - mean * mean;
    float rstd = rsqrtf(var + 1e-5f);

    const int r = row % L_;
    const float *gg, *bb;
    if (r < S_)            { gg = gs; bb = bs; }
    else if (r >= L_ - S_) { gg = ge; bb = be; }
    else                   { gg = g0; bb = b0; }
    float4 ga = ((const float4*)gg)[lane], gb = ((const float4*)gg)[lane + 64];
    float4 ba = ((const float4*)bb)[lane], bb4 = ((const float4*)bb)[lane + 64];

    float n0[4], n1[4];
    n0[0] = (v0.x - mean) * rstd * ga.x + ba.x;
    n0[1] = (v0.y - mean) * rstd * ga.y + ba.y;
    n0[2] = (v0.z - mean) * rstd * ga.z + ba.z;
    n0[3] = (v0.w - mean) * rstd * ga.w + ba.w;
    n1[0] = (v1.x - mean) * rstd * gb.x + bb4.x;
    n1[1] = (v1.y - mean) * rstd * gb.y + bb4.y;
    n1[2] = (v1.z - mean) * rstd * gb.z + bb4.z;
    n1[3] = (v1.w - mean) * rstd * gb.w + bb4.w;

    union { uint2 u; f16 h[4]; } h0, h1, l0, l1;
    #pragma unroll
    for (int i = 0; i < 4; ++i) {
        h0.h[i] = (f16)n0[i]; l0.h[i] = (f16)(n0[i] - (float)h0.h[i]);
        h1.h[i] = (f16)n1[i]; l1.h[i] = (f16)(n1[i] - (float)h1.h[i]);
    }
    f16* ph = xh + (size_t)row * DIN;
    f16* pl = xl + (size_t)row * DIN;
    *(uint2*)(ph + 4 * lane)       = h0.u;
    *(uint2*)(ph + 256 + 4 * lane) = h1.u;
    *(uint2*)(pl + 4 * lane)       = l0.u;
    *(uint2*)(pl + 256 + 4 * lane) = l1.u;
}

// ---------------------------------------------------------------------------
// k_proj: QKV via split-fp16 MFMA (3 terms for q,k; 1 for v). grid (144,3).
// ---------------------------------------------------------------------------
__global__ __launch_bounds__(256) void k_proj(
    const f16* __restrict__ xh, const f16* __restrict__ xl,
    const float* __restrict__ Wq,  const float* __restrict__ Wk,  const float* __restrict__ Wv,
    const float* __restrict__ Wqs, const float* __restrict__ Wks, const float* __restrict__ Wvs,
    const float* __restrict__ Wqe, const float* __restrict__ Wke, const float* __restrict__ Wve,
    float* __restrict__ qf, float* __restrict__ kf, float* __restrict__ vf,
    f16* __restrict__ qsp, f16* __restrict__ ksp, f16* __restrict__ vhT)
{
    __shared__ f16 As[64 * 136];
    __shared__ f16 Bs[64 * 136];
    const int tid  = threadIdx.x;
    const int row0 = blockIdx.x * 64;
    const int rseq = row0 % L_;
    const int seg  = (rseq < S_) ? 0 : (rseq >= L_ - S_) ? 2 : 1;
    const int m    = blockIdx.y;
    const float* W;
    float* outf;
    if (m == 0)      { W = (seg == 0) ? Wqs : (seg == 2) ? Wqe : Wq; outf = qf; }
    else if (m == 1) { W = (seg == 0) ? Wks : (seg == 2) ? Wke : Wk; outf = kf; }
    else             { W = (seg == 0) ? Wvs : (seg == 2) ? Wve : Wv; outf = vf; }

    const int w = tid >> 6, lane = tid & 63;
    const int cl = lane & 15, quad = lane >> 4;
    const int r0 = 32 * (w >> 1), c0 = 32 * (w & 1);

    f32x4 acc[2][2];
    #pragma unroll
    for (int i = 0; i < 2; ++i)
        #pragma unroll
        for (int j = 0; j < 2; ++j) acc[i][j] = 0.f;

    for (int kc = 0; kc < DIN; kc += 64) {
        __syncthreads();
        #pragma unroll
        for (int i = 0; i < 2; ++i) {
            int g = tid + 256 * i;
            int r = g >> 3, c = g & 7;
            *(uint4*)(As + r * 136 + c * 8) =
                *(const uint4*)(xh + (size_t)(row0 + r) * DIN + kc + c * 8);
            *(uint4*)(As + r * 136 + 64 + c * 8) =
                *(const uint4*)(xl + (size_t)(row0 + r) * DIN + kc + c * 8);
        }
        #pragma unroll
        for (int i = 0; i < 4; ++i) {
            int g = tid + 256 * i;
            int k = g >> 4, c4 = g & 15;
            float4 wv = ((const float4*)W)[(size_t)(kc + k) * 16 + c4];
            f16 h0 = (f16)wv.x, h1 = (f16)wv.y, h2 = (f16)wv.z, h3 = (f16)wv.w;
            Bs[(c4 * 4 + 0) * 136 + k] = h0;
            Bs[(c4 * 4 + 1) * 136 + k] = h1;
            Bs[(c4 * 4 + 2) * 136 + k] = h2;
            Bs[(c4 * 4 + 3) * 136 + k] = h3;
            Bs[(c4 * 4 + 0) * 136 + 64 + k] = (f16)(wv.x - (float)h0);
            Bs[(c4 * 4 + 1) * 136 + 64 + k] = (f16)(wv.y - (float)h1);
            Bs[(c4 * 4 + 2) * 136 + 64 + k] = (f16)(wv.z - (float)h2);
            Bs[(c4 * 4 + 3) * 136 + 64 + k] = (f16)(wv.w - (float)h3);
        }
        __syncthreads();
        #pragma unroll
        for (int h = 0; h < 2; ++h) {
            half8 ah[2], al[2], bh[2], bl[2];
            #pragma unroll
            for (int rs = 0; rs < 2; ++rs) {
                const f16* base = As + (r0 + 16 * rs + cl) * 136 + h * 32 + quad * 8;
                ah[rs] = *(const half8*)(base);
                al[rs] = *(const half8*)(base + 64);
            }
            #pragma unroll
            for (int cs = 0; cs < 2; ++cs) {
                const f16* base = Bs + (c0 + 16 * cs + cl) * 136 + h * 32 + quad * 8;
                bh[cs] = *(const half8*)(base);
                bl[cs] = *(const half8*)(base + 64);
            }
            #pragma unroll
            for (int rs = 0; rs < 2; ++rs)
                #pragma unroll
                for (int cs = 0; cs < 2; ++cs) {
                    acc[rs][cs] = __builtin_amdgcn_mfma_f32_16x16x32_f16(ah[rs], bh[cs], acc[rs][cs], 0, 0, 0);
                    if (m < 2) {
                        acc[rs][cs] = __builtin_amdgcn_mfma_f32_16x16x32_f16(ah[rs], bl[cs], acc[rs][cs], 0, 0, 0);
                        acc[rs][cs] = __builtin_amdgcn_mfma_f32_16x16x32_f16(al[rs], bh[cs], acc[rs][cs], 0, 0, 0);
                    }
                }
        }
    }

    const int bI = row0 / L_;
    const int rb = row0 - bI * L_;
    f16* sp = (m == 0) ? qsp : ksp;
    #pragma unroll
    for (int rs = 0; rs < 2; ++rs)
        #pragma unroll
        for (int cs = 0; cs < 2; ++cs)
            #pragma unroll
            for (int r = 0; r < 4; ++r) {
                int lrow = r0 + 16 * rs + quad * 4 + r;
                int col  = c0 + 16 * cs + cl;
                float v  = acc[rs][cs][r];
                size_t grow = (size_t)(row0 + lrow);
                outf[grow * DK + col] = v;
                if (m < 2) {
                    f16 hv = (f16)v;
                    sp[grow * 128 + col]      = hv;
                    sp[grow * 128 + 64 + col] = (f16)(v - (float)hv);
                } else {
                    vhT[(size_t)(bI * 64 + col) * L_ + rb + lrow] = (f16)v;
                }
            }
}

// ---------------------------------------------------------------------------
// k_cope: Li[gr][p] = q_mid[gr] . cope[:,p]. grid 256 x 256. (round-4 verified)
// ---------------------------------------------------------------------------
__global__ __launch_bounds__(256) void k_cope(
    const float* __restrict__ qf, const float* __restrict__ cope,
    float* __restrict__ Li)
{
    __shared__ float qs[32 * 68];
    const int tid = threadIdx.x;
    const int gr0 = blockIdx.x * 32;
    const int b   = gr0 >> 11;
    const size_t qrow0 = (size_t)b * L_ + S_ + (gr0 & 2047);
    #pragma unroll
    for (int i = 0; i < 2; ++i) {
        int g = tid + 256 * i;
        int r = g >> 4, f = g & 15;
        *(float4*)(qs + r * 68 + f * 4) = ((const float4*)qf)[(qrow0 + r) * 16 + f];
    }
    __syncthreads();
    const int c4 = tid & 31, r4 = tid >> 5;
    float acc[4][4] = {};
    for (int d = 0; d < DK; ++d) {
        float4 cv = ((const float4*)cope)[d * 32 + c4];
        #pragma unroll
        for (int i = 0; i < 4; ++i) {
            float a = qs[(r4 * 4 + i) * 68 + d];
            acc[i][0] += a * cv.x; acc[i][1] += a * cv.y;
            acc[i][2] += a * cv.z; acc[i][3] += a * cv.w;
        }
    }
    #pragma unroll
    for (int i = 0; i < 4; ++i)
        *(float4*)(Li + (size_t)(gr0 + r4 * 4 + i) * 128 + c4 * 4) =
            make_float4(acc[i][0], acc[i][1], acc[i][2], acc[i][3]);
}

// ---------------------------------------------------------------------------
// k_gates: full mid rectangle dots via split-fp16 MFMA; per-(row,chunk)
// gate sums into G[8192][32]. grid (64, 32) x 256. (k_dots body)
// ---------------------------------------------------------------------------
__global__ __launch_bounds__(256) void k_gates(
    const f16* __restrict__ qsp, const f16* __restrict__ ksp,
    float* __restrict__ G)
{
    __shared__ f16 Qs[128 * 136];
    __shared__ f16 Ks[64 * 136];
    const int tid = threadIdx.x;
    const int gr0 = blockIdx.x * 128;
    const int chm = blockIdx.y;            // mid chunk 0..31
    const int b   = gr0 >> 11;
    const size_t qrow0 = (size_t)b * L_ + S_ + (gr0 & 2047);
    const size_t krow0 = (size_t)b * L_ + S_ + chm * 64;

    #pragma unroll
    for (int i = 0; i < 8; ++i) {
        int g = tid + 256 * i;
        int r = g >> 4, c = g & 15;
        *(uint4*)(Qs + r * 136 + c * 8) = *(const uint4*)(qsp + (qrow0 + r) * 128 + c * 8);
    }
    #pragma unroll
    for (int i = 0; i < 4; ++i) {
        int g = tid + 256 * i;
        int r = g >> 4, c = g & 15;
        *(uint4*)(Ks + r * 136 + c * 8) = *(const uint4*)(ksp + (krow0 + r) * 128 + c * 8);
    }
    __syncthreads();

    const int w = tid >> 6, lane = tid & 63;
    const int cl = lane & 15, quad = lane >> 4;

    f32x4 acc[2][4];
    #pragma unroll
    for (int i = 0; i < 2; ++i)
        #pragma unroll
        for (int j = 0; j < 4; ++j) acc[i][j] = 0.f;

    #pragma unroll
    for (int h = 0; h < 2; ++h) {
        half8 ah[2], al[2], bh[4], bl[4];
        #pragma unroll
        for (int rs = 0; rs < 2; ++rs) {
            const f16* base = Qs + (32 * w + 16 * rs + cl) * 136 + h * 32 + quad * 8;
            ah[rs] = *(const half8*)(base);
            al[rs] = *(const half8*)(base + 64);
        }
        #pragma unroll
        for (int c = 0; c < 4; ++c) {
            const f16* base = Ks + (16 * c + cl) * 136 + h * 32 + quad * 8;
            bh[c] = *(const half8*)(base);
            bl[c] = *(const half8*)(base + 64);
        }
        #pragma unroll
        for (int rs = 0; rs < 2; ++rs)
            #pragma unroll
            for (int c = 0; c < 4; ++c) {
                acc[rs][c] = __builtin_amdgcn_mfma_f32_16x16x32_f16(ah[rs], bh[c], acc[rs][c], 0, 0, 0);
                acc[rs][c] = __builtin_amdgcn_mfma_f32_16x16x32_f16(ah[rs], bl[c], acc[rs][c], 0, 0, 0);
                acc[rs][c] = __builtin_amdgcn_mfma_f32_16x16x32_f16(al[rs], bh[c], acc[rs][c], 0, 0, 0);
            }
    }

    #pragma unroll
    for (int rs = 0; rs < 2; ++rs)
        #pragma unroll
        for (int r = 0; r < 4; ++r) {
            float s = 0.f;
            #pragma unroll
            for (int c = 0; c < 4; ++c)
                s += 1.f / (1.f + __expf(-acc[rs][c][r]));
            #pragma unroll
            for (int off = 1; off < 16; off <<= 1) s += __shfl_xor(s, off);
            if (cl == 0)
                G[(size_t)(gr0 + 32 * w + 16 * rs + quad * 4 + r) * 32 + chm] = s;
        }
}

// ---------------------------------------------------------------------------
// k_suffix: R[row][ch] = sum_{ch'>ch} G[row][ch']. grid 32 x 256.
// ---------------------------------------------------------------------------
__global__ __launch_bounds__(256) void k_suffix(
    const float* __restrict__ G, float* __restrict__ R)
{
    const int row = blockIdx.x * 256 + threadIdx.x;
    float v[32];
    #pragma unroll
    for (int i = 0; i < 8; ++i)
        *(float4*)&v[i * 4] = ((const float4*)G)[(size_t)row * 8 + i];
    float run = 0.f;
    #pragma unroll
    for (int ch = 31; ch >= 0; --ch) { float t = v[ch]; v[ch] = run; run += t; }
    #pragma unroll
    for (int i = 0; i < 8; ++i)
        ((float4*)R)[(size_t)row * 8 + i] = *(const float4*)&v[i * 4];
}

// ---------------------------------------------------------------------------
// k_flash: fused dots-recompute + CoPE bias + online softmax + PV,
// 4-way K-split with flash-decoding merge. grid (128, 4) x 256.
// Block: 64 q-rows; wave w owns rows 16w..16w+15.
// ---------------------------------------------------------------------------
__global__ __launch_bounds__(256) void k_flash(
    const f16* __restrict__ qsp, const f16* __restrict__ ksp,
    const f16* __restrict__ vhT, const float* __restrict__ Li,
    const float* __restrict__ R,
    float* __restrict__ Opart, float2* __restrict__ Ml)
{
    __shared__ f16  Qs[64 * 136];
    __shared__ f16  Ks[64 * 136];
    __shared__ f16  Ps[64 * 72];
    __shared__ f16  Vt[64 * 72];
    __shared__ f16  LiS[64 * 128];
    __shared__ float Rs[64 * 32];

    const int tid = threadIdx.x;
    const int gr0 = blockIdx.x * 64;
    const int ks  = blockIdx.y;
    const int b   = gr0 >> 11, q0 = gr0 & 2047;
    const size_t qrow0 = (size_t)b * L_ + S_ + q0;

    const int cmax = (191 + q0) >> 6;
    const int c_beg = ks * 9;
    int c_end = c_beg + 9;
    if (c_end > 34) c_end = 34;
    if (c_end > cmax + 1) c_end = cmax + 1;

    // stage Q split, Li (fp16), R
    #pragma unroll
    for (int i = 0; i < 4; ++i) {
        int g = tid + 256 * i;             // 64 rows x 16 uint4
        int r = g >> 4, c = g & 15;
        *(uint4*)(Qs + r * 136 + c * 8) = *(const uint4*)(qsp + (qrow0 + r) * 128 + c * 8);
    }
    #pragma unroll
    for (int i = 0; i < 8; ++i) {
        int g = tid + 256 * i;             // 64 rows x 32 float4
        int r = g >> 5, c4 = g & 31;
        float4 lv = ((const float4*)Li)[(size_t)(gr0 + r) * 32 + c4];
        LiS[r * 128 + c4 * 4 + 0] = (f16)lv.x;
        LiS[r * 128 + c4 * 4 + 1] = (f16)lv.y;
        LiS[r * 128 + c4 * 4 + 2] = (f16)lv.z;
        LiS[r * 128 + c4 * 4 + 3] = (f16)lv.w;
    }
    #pragma unroll
    for (int i = 0; i < 2; ++i) {
        int g = tid + 256 * i;             // 64 rows x 8 float4
        int r = g >> 3, c4 = g & 7;
        ((float4*)Rs)[r * 8 + c4] = ((const float4*)R)[(size_t)(gr0 + r) * 8 + c4];
    }

    const int w = tid >> 6, lane = tid & 63;
    const int cl = lane & 15, quad = lane >> 4;

    float m4[4], l4[4];
    f32x4 oacc[4];
    #pragma unroll
    for (int r = 0; r < 4; ++r) { m4[r] = NEGINF; l4[r] = 0.f; }
    #pragma unroll
    for (int cd = 0; cd < 4; ++cd) oacc[cd] = 0.f;

    for (int ch = c_beg; ch < c_end; ++ch) {
        __syncthreads();
        #pragma unroll
        for (int i = 0; i < 4; ++i) {
            int g = tid + 256 * i;         // 64 key-rows x 16 uint4
            int r = g >> 4, c = g & 15;
            *(uint4*)(Ks + r * 136 + c * 8) =
                *(const uint4*)(ksp + (size_t)(b * L_ + 64 * ch + r) * 128 + c * 8);
        }
        #pragma unroll
        for (int i = 0; i < 2; ++i) {
            int g = tid + 256 * i;         // 64 dims x 8 uint4
            int r = g >> 3, c = g & 7;
            *(uint4*)(Vt + r * 72 + c * 8) =
                *(const uint4*)(vhT + (size_t)(b * 64 + r) * L_ + 64 * ch + c * 8);
        }
        __syncthreads();

        // dots (split, 3 terms): d[c][r] = dot[row=16w+quad*4+r][col=64ch+16c+cl]
        f32x4 d[4];
        #pragma unroll
        for (int c = 0; c < 4; ++c) d[c] = 0.f;
        #pragma unroll
        for (int h = 0; h < 2; ++h) {
            const f16* abase = Qs + (16 * w + cl) * 136 + h * 32 + quad * 8;
            half8 ah = *(const half8*)(abase);
            half8 al = *(const half8*)(abase + 64);
            #pragma unroll
            for (int c = 0; c < 4; ++c) {
                const f16* bbase = Ks + (16 * c + cl) * 136 + h * 32 + quad * 8;
                half8 bh = *(const half8*)(bbase);
                half8 bl = *(const half8*)(bbase + 64);
                d[c] = __builtin_amdgcn_mfma_f32_16x16x32_f16(ah, bh, d[c], 0, 0, 0);
                d[c] = __builtin_amdgcn_mfma_f32_16x16x32_f16(ah, bl, d[c], 0, 0, 0);
                d[c] = __builtin_amdgcn_mfma_f32_16x16x32_f16(al, bh, d[c], 0, 0, 0);
            }
        }

        // scores p[c][r] (overwrite d)
        if (ch >= 2) {
            const int chm = ch - 2;
            float ts[4][4], incl[4][4];
            #pragma unroll
            for (int c = 0; c < 4; ++c)
                #pragma unroll
                for (int r = 0; r < 4; ++r) {
                    float gg = 1.f / (1.f + __expf(-d[c][r]));
                    float inc = gg;
                    #pragma unroll
                    for (int off = 1; off < 16; off <<= 1) {
                        float u = __shfl_down(inc, off);
                        if (cl + off < 16) inc += u;
                    }
                    incl[c][r] = inc;                       // inclusive suffix over cl
                    ts[c][r]   = __shfl(inc, quad << 4);    // tile total (cl=0)
                }
            #pragma unroll
            for (int r = 0; r < 4; ++r) {
                const int lr = 16 * w + quad * 4 + r;
                float T[4];
                T[3] = 0.f;
                T[2] = ts[3][r];
                T[1] = T[2] + ts[2][r];
                T[0] = T[1] + ts[1][r];
                float rsuf = Rs[lr * 32 + chm];
                #pragma unroll
                for (int c = 0; c < 4; ++c) {
                    float suf = incl[c][r] + T[c] + rsuf;
                    float pos = fminf(suf, (float)(S_ - 1));
                    int   ifl = (int)pos;
                    int   ic  = (int)ceilf(pos);
                    float wfr = pos - (float)ifl;
                    float bias = (float)LiS[lr * 128 + ic] * wfr
                               + (float)LiS[lr * 128 + ifl] * (1.f - wfr);
                    int jmid = 64 * ch + 16 * c + cl - 128;
                    d[c][r] = (jmid <= q0 + lr) ? d[c][r] * SCALE + bias : NEGINF;
                }
            }
        } else {
            #pragma unroll
            for (int c = 0; c < 4; ++c)
                #pragma unroll
                for (int r = 0; r < 4; ++r) d[c][r] *= SCALE;
        }

        // online softmax per row
        #pragma unroll
        for (int r = 0; r < 4; ++r) {
            float mx = d[0][r];
            #pragma unroll
            for (int c = 1; c < 4; ++c) mx = fmaxf(mx, d[c][r]);
            #pragma unroll
            for (int off = 1; off < 16; off <<= 1) mx = fmaxf(mx, __shfl_xor(mx, off));
            float mnew  = fmaxf(m4[r], mx);
            float alpha = __expf(m4[r] - mnew);
            m4[r] = mnew;
            float es = 0.f;
            #pragma unroll
            for (int c = 0; c < 4; ++c) {
                float e = (d[c][r] <= -1e29f) ? 0.f : __expf(d[c][r] - mnew);
                Ps[(16 * w + quad * 4 + r) * 72 + 16 * c + cl] = (f16)e;
                es += e;
            }
            #pragma unroll
            for (int off = 1; off < 16; off <<= 1) es += __shfl_xor(es, off);
            l4[r] = l4[r] * alpha + es;
            #pragma unroll
            for (int cd = 0; cd < 4; ++cd) oacc[cd][r] *= alpha;
        }
        __syncthreads();

        // PV
        #pragma unroll
        for (int h = 0; h < 2; ++h) {
            half8 a = *(const half8*)(Ps + (16 * w + cl) * 72 + h * 32 + quad * 8);
            #pragma unroll
            for (int cd = 0; cd < 4; ++cd) {
                half8 bv = *(const half8*)(Vt + (16 * cd + cl) * 72 + h * 32 + quad * 8);
                oacc[cd] = __builtin_amdgcn_mfma_f32_16x16x32_f16(a, bv, oacc[cd], 0, 0, 0);
            }
        }
    }

    // epilogue
    #pragma unroll
    for (int cd = 0; cd < 4; ++cd)
        #pragma unroll
        for (int r = 0; r < 4; ++r) {
            int mrow = gr0 + 16 * w + quad * 4 + r;
            Opart[((size_t)ks * NMID + mrow) * DK + 16 * cd + cl] = oacc[cd][r];
        }
    if (cl == 0) {
        #pragma unroll
        for (int r = 0; r < 4; ++r) {
            int mrow = gr0 + 16 * w + quad * 4 + r;
            Ml[(size_t)ks * NMID + mrow] = make_float2(m4[r], l4[r]);
        }
    }
}

// ---------------------------------------------------------------------------
// k_merge: flash-decoding combine of 4 partials. grid 2048 x 256.
// ---------------------------------------------------------------------------
__global__ __launch_bounds__(256) void k_merge(
    const float* __restrict__ Opart, const float2* __restrict__ Ml,
    float* __restrict__ out)
{
    const int e  = blockIdx.x * 256 + threadIdx.x;
    const int gr = e >> 6, c = e & 63;
    const int b  = gr >> 11, q = gr & 2047;
    float2 ml[4];
    #pragma unroll
    for (int i = 0; i < 4; ++i) ml[i] = Ml[(size_t)i * NMID + gr];
    float M = ml[0].x;
    #pragma unroll
    for (int i = 1; i < 4; ++i) M = fmaxf(M, ml[i].x);
    float num = 0.f, den = 0.f;
    #pragma unroll
    for (int i = 0; i < 4; ++i) {
        float sc = __expf(ml[i].x - M);
        den += sc * ml[i].y;
        num += sc * Opart[((size_t)i * NMID + gr) * DK + c];
    }
    out[((size_t)b * L_ + S_ + q) * DK + c] = num / den;
}

// ---------------------------------------------------------------------------
// k_dots_edge / k_soft_edge / k_pv_edge / k_merge_edge (unchanged, verified)
// ---------------------------------------------------------------------------
__global__ __launch_bounds__(256) void k_dots_edge(
    const float* __restrict__ qf, const float* __restrict__ kf,
    float* __restrict__ De)
{
    const int bx   = blockIdx.x;
    const int b    = bx >> 1;
    const int half = bx & 1;
    const int col0 = blockIdx.y * 128;
    if (half == 0 && col0 > 127) return;

    __shared__ float Qs[128 * 68];
    __shared__ float Kt[64 * 136];
    const int tid = threadIdx.x;
    const int er0 = bx * 128;
    const size_t qrow0 = (size_t)b * L_ + (half ? 2176 : 0);
    const size_t krow0 = (size_t)b * L_ + col0;

    #pragma unroll
    for (int i = 0; i < 8; ++i) {
        int g = tid + 256 * i;
        int r = g >> 4, f = g & 15;
        *(float4*)(Qs + r * 68 + f * 4) = ((const float4*)qf)[(qrow0 + r) * 16 + f];
    }
    #pragma unroll
    for (int i = 0; i < 8; ++i) {
        int g = tid + 256 * i;
        int j = g >> 4, f = g & 15;
        float4 kv = ((const float4*)kf)[(krow0 + j) * 16 + f];
        Kt[(f * 4 + 0) * 136 + j] = kv.x;
        Kt[(f * 4 + 1) * 136 + j] = kv.y;
        Kt[(f * 4 + 2) * 136 + j] = kv.z;
        Kt[(f * 4 + 3) * 136 + j] = kv.w;
    }
    __syncthreads();

    const int c8 = tid & 15, r8 = tid >> 4;
    float acc[8][8] = {};
    for (int d0 = 0; d0 < 64; d0 += 4) {
        float4 a[8];
        #pragma unroll
        for (int i = 0; i < 8; ++i)
            a[i] = *(const float4*)(Qs + (r8 * 8 + i) * 68 + d0);
        #pragma unroll
        for (int dd = 0; dd < 4; ++dd) {
            float4 k0 = *(const float4*)(Kt + (d0 + dd) * 136 + c8 * 8);
            float4 k1 = *(const float4*)(Kt + (d0 + dd) * 136 + c8 * 8 + 4);
            #pragma unroll
            for (int i = 0; i < 8; ++i) {
                float av = (dd == 0) ? a[i].x : (dd == 1) ? a[i].y : (dd == 2) ? a[i].z : a[i].w;
                acc[i][0] += av * k0.x; acc[i][1] += av * k0.y;
                acc[i][2] += av * k0.z; acc[i][3] += av * k0.w;
                acc[i][4] += av * k1.x; acc[i][5] += av * k1.y;
                acc[i][6] += av * k1.z; acc[i][7] += av * k1.w;
            }
        }
    }
    #pragma unroll
    for (int i = 0; i < 8; ++i) {
        size_t o = (size_t)(er0 + r8 * 8 + i) * LE + col0 + c8 * 8;
        *(float4*)(De + o)     = make_float4(acc[i][0], acc[i][1], acc[i][2], acc[i][3]);
        *(float4*)(De + o + 4) = make_float4(acc[i][4], acc[i][5], acc[i][6], acc[i][7]);
    }
}

__global__ __launch_bounds__(256) void k_soft_edge(float* __restrict__ De)
{
    __shared__ float red[256];
    const int tid = threadIdx.x;
    const int er  = blockIdx.x;
    const int r   = er & 255;
    const int Q   = (r < 128) ? r : (2048 + r);
    const size_t rowoff = (size_t)er * LE;

    float v[9];
    #pragma unroll
    for (int i = 0; i < 9; ++i) {
        int j = tid + 256 * i;
        float d = De[rowoff + j];
        v[i] = (j <= Q) ? d * SCALE : NEGINF;
    }
    float mx = v[0];
    #pragma unroll
    for (int i = 1; i < 9; ++i) mx = fmaxf(mx, v[i]);
    red[tid] = mx;
    __syncthreads();
    for (int off = 128; off > 0; off >>= 1) {
        if (tid < off) red[tid] = fmaxf(red[tid], red[tid + off]);
        __syncthreads();
    }
    mx = red[0];
    __syncthreads();

    float lsum = 0.f;
    #pragma unroll
    for (int i = 0; i < 9; ++i) {
        v[i] = __expf(v[i] - mx);
        lsum += v[i];
    }
    red[tid] = lsum;
    __syncthreads();
    for (int off = 128; off > 0; off >>= 1) {
        if (tid < off) red[tid] += red[tid + off];
        __syncthreads();
    }
    float inv = 1.f / red[0];
    #pragma unroll
    for (int i = 0; i < 9; ++i)
        De[rowoff + tid + 256 * i] = v[i] * inv;
}

__global__ __launch_bounds__(256) void k_pv_edge(
    const float* __restrict__ De, const float* __restrict__ vf,
    float* __restrict__ Oe)
{
    __shared__ float Ps[32 * 68];
    __shared__ float Vs[64 * 68];
    const int tid = threadIdx.x;
    const int er0 = blockIdx.x * 32;
    const int ks  = blockIdx.y;
    const int b   = er0 >> 8, r0 = er0 & 255;
    const int Qmax = (r0 < 128) ? (r0 + 31) : (2048 + r0 + 31);
    const int cmax = Qmax >> 6;
    const int c_beg = ks * 9;
    int c_end = c_beg + 9;
    if (c_end > 36) c_end = 36;
    if (c_end > cmax + 1) c_end = cmax + 1;

    const int c4 = tid & 15, rg = tid >> 4;
    float acc[2][4] = {};

    for (int ch = c_beg; ch < c_end; ++ch) {
        __syncthreads();
        #pragma unroll
        for (int i = 0; i < 2; ++i) {
            int g = tid + 256 * i;
            int r = g >> 4, f = g & 15;
            *(float4*)(Ps + r * 68 + f * 4) =
                *(const float4*)(De + (size_t)(er0 + r) * LE + ch * 64 + f * 4);
        }
        #pragma unroll
        for (int i = 0; i < 4; ++i) {
            int g = tid + 256 * i;
            int j = g >> 4, f = g & 15;
            *(float4*)(Vs + j * 68 + f * 4) =
                *(const float4*)(vf + (size_t)(b * L_ + ch * 64 + j) * DK + f * 4);
        }
        __syncthreads();
        #pragma unroll 4
        for (int j = 0; j < 64; ++j) {
            float4 vv = *(const float4*)(Vs + j * 68 + c4 * 4);
            float p0 = Ps[(rg * 2 + 0) * 68 + j];
            float p1 = Ps[(rg * 2 + 1) * 68 + j];
            acc[0][0] += p0 * vv.x; acc[0][1] += p0 * vv.y;
            acc[0][2] += p0 * vv.z; acc[0][3] += p0 * vv.w;
            acc[1][0] += p1 * vv.x; acc[1][1] += p1 * vv.y;
            acc[1][2] += p1 * vv.z; acc[1][3] += p1 * vv.w;
        }
    }
    #pragma unroll
    for (int i = 0; i < 2; ++i)
        *(float4*)(Oe + ((size_t)ks * NEDGE + er0 + rg * 2 + i) * DK + c4 * 4) =
            make_float4(acc[i][0], acc[i][1], acc[i][2], acc[i][3]);
}

__global__ __launch_bounds__(256) void k_merge_edge(
    const float* __restrict__ Oe, float* __restrict__ out)
{
    const int e  = blockIdx.x * 256 + threadIdx.x;
    const int er = e >> 6, c = e & 63;
    const int b  = er >> 8, r = er & 255;
    const int gQ = (r < 128) ? r : (2048 + r);
    const int NP = NEDGE * DK;
    float s = Oe[e] + Oe[e + NP] + Oe[e + 2 * NP] + Oe[e + 3 * NP];
    out[((size_t)b * L_ + gQ) * DK + c] = s;
}

// ---------------------------------------------------------------------------
extern "C" void kernel_launch(void* const* d_in, const int* in_sizes, int n_in,
                              void* d_out, int out_size, void* d_ws, size_t ws_size,
                              hipStream_t stream)
{
    const float* x    = (const float*)d_in[0];
    const float* Wq   = (const float*)d_in[1];
    const float* Wk   = (const float*)d_in[2];
    const float* Wv   = (const float*)d_in[3];
    const float* Wqs  = (const float*)d_in[4];
    const float* Wks  = (const float*)d_in[5];
    const float* Wvs  = (const float*)d_in[6];
    const float* Wqe  = (const float*)d_in[7];
    const float* Wke  = (const float*)d_in[8];
    const float* Wve  = (const float*)d_in[9];
    const float* g0   = (const float*)d_in[10];
    const float* b0   = (const float*)d_in[11];
    const float* gs   = (const float*)d_in[12];
    const float* bs   = (const float*)d_in[13];
    const float* ge   = (const float*)d_in[14];
    const float* be   = (const float*)d_in[15];
    const float* cope = (const float*)d_in[16];

    const size_t NR = (size_t)B_ * L_;               // 9216 rows
    float* ws = (float*)d_ws;
    float* qf    = ws;                               // 9216*64 f32
    float* kf    = qf + NR * DK;
    float* vf    = kf + NR * DK;
    float* Opart = vf + NR * DK;                     // 4*8192*64 f32
    float2* Ml   = (float2*)(Opart + (size_t)4 * NMID * DK);  // 4*8192 float2
    float* Li    = (float*)(Ml + (size_t)4 * NMID);  // 8192*128 f32
    float* G     = Li + (size_t)NMID * 128;          // 8192*32 f32
    float* R     = G + (size_t)NMID * 32;            // 8192*32 f32
    f16*   qsp   = (f16*)(R + (size_t)NMID * 32);    // 9216*128 h (hi|lo)
    f16*   ksp   = qsp + NR * 128;
    f16*   vhT   = ksp + NR * 128;                   // 4*64*2304 h
    float* De    = (float*)(vhT + NR * DK);          // 1024*2304 f32 (edge)
    // xh/xl overlap De's region + beyond (both dead before De is written)
    f16*   xh    = (f16*)De;                         // 9216*512 h
    f16*   xl    = xh + NR * DIN;                    // 9216*512 h
    float* Oe    = Opart;                            // edge reuses Opart after k_merge
    float* out   = (float*)d_out;

    k_ln  <<<L_ * B_ / 4, 256, 0, stream>>>(x, g0, b0, gs, bs, ge, be, xh, xl);
    k_proj<<<dim3(144, 3), 256, 0, stream>>>(xh, xl, Wq, Wk, Wv, Wqs, Wks, Wvs,
                                             Wqe, Wke, Wve, qf, kf, vf,
                                             qsp, ksp, vhT);
    k_cope<<<NMID / 32, 256, 0, stream>>>(qf, cope, Li);
    k_gates<<<dim3(NMID / 128, 32), 256, 0, stream>>>(qsp, ksp, G);
    k_suffix<<<NMID / 256, 256, 0, stream>>>(G, R);
    k_flash<<<dim3(NMID / 64, 4), 256, 0, stream>>>(qsp, ksp, vhT, Li, R, Opart, Ml);
    k_merge<<<NMID * DK / 256, 256, 0, stream>>>(Opart, Ml, out);
    // edge path
    k_dots_edge<<<dim3(8, 18), 256, 0, stream>>>(qf, kf, De);
    k_soft_edge<<<NEDGE, 256, 0, stream>>>(De);
    k_pv_edge<<<dim3(NEDGE / 32, 4), 256, 0, stream>>>(De, vf, Oe);
    k_merge_edge<<<NEDGE * DK / 256, 256, 0, stream>>>(Oe, out);
}

// Round 10
// 223.212 us; speedup vs baseline: 1.1588x; 1.1588x over previous
//
#include <hip/hip_runtime.h>
#include <math.h>

#define B_    4
#define SEQ_  2048
#define S_    128
#define L_    2304          // SEQ + 2*S
#define DIN   512
#define DK    64
#define NEGINF (-1e30f)
#define SCALE 0.125f
#define NCOLS 2176          // start(128) + mid(2048) key columns in D
#define NMID  8192          // B_*SEQ_
#define NEDGE 1024          // B_*2*S_
#define LE    2304          // edge D row length (f32)
#define PROWS 4352          // fp16 pitch inside an fp32 D row
#define PEPITCH 4608        // fp16 pitch inside an fp32 De row

typedef _Float16 f16;
typedef __attribute__((ext_vector_type(8))) _Float16 half8;
typedef __attribute__((ext_vector_type(4))) float f32x4;

union U4 { uint4 u; f16 h[8]; };

// ---------------------------------------------------------------------------
// k_ln: wave-per-row LayerNorm, writes hi/lo fp16 split of xn.
// ---------------------------------------------------------------------------
__global__ __launch_bounds__(256) void k_ln(
    const float* __restrict__ x,
    const float* __restrict__ g0, const float* __restrict__ b0,
    const float* __restrict__ gs, const float* __restrict__ bs,
    const float* __restrict__ ge, const float* __restrict__ be,
    f16* __restrict__ xh, f16* __restrict__ xl)
{
    const int wave = threadIdx.x >> 6, lane = threadIdx.x & 63;
    const int row  = blockIdx.x * 4 + wave;
    const float4* xr = (const float4*)(x + (size_t)row * DIN);
    float4 v0 = xr[lane], v1 = xr[lane + 64];
    float s  = v0.x + v0.y + v0.z + v0.w + v1.x + v1.y + v1.z + v1.w;
    float s2 = v0.x*v0.x + v0.y*v0.y + v0.z*v0.z + v0.w*v0.w
             + v1.x*v1.x + v1.y*v1.y + v1.z*v1.z + v1.w*v1.w;
    #pragma unroll
    for (int m = 1; m < 64; m <<= 1) { s += __shfl_xor(s, m); s2 += __shfl_xor(s2, m); }
    float mean = s * (1.f / DIN);
    float var  = s2 * (1.f / DIN) - mean * mean;
    float rstd = rsqrtf(var + 1e-5f);

    const int r = row % L_;
    const float *gg, *bb;
    if (r < S_)            { gg = gs; bb = bs; }
    else if (r >= L_ - S_) { gg = ge; bb = be; }
    else                   { gg = g0; bb = b0; }
    float4 ga = ((const float4*)gg)[lane], gb = ((const float4*)gg)[lane + 64];
    float4 ba = ((const float4*)bb)[lane], bb4 = ((const float4*)bb)[lane + 64];

    float n0[4], n1[4];
    n0[0] = (v0.x - mean) * rstd * ga.x + ba.x;
    n0[1] = (v0.y - mean) * rstd * ga.y + ba.y;
    n0[2] = (v0.z - mean) * rstd * ga.z + ba.z;
    n0[3] = (v0.w - mean) * rstd * ga.w + ba.w;
    n1[0] = (v1.x - mean) * rstd * gb.x + bb4.x;
    n1[1] = (v1.y - mean) * rstd * gb.y + bb4.y;
    n1[2] = (v1.z - mean) * rstd * gb.z + bb4.z;
    n1[3] = (v1.w - mean) * rstd * gb.w + bb4.w;

    union { uint2 u; f16 h[4]; } h0, h1, l0, l1;
    #pragma unroll
    for (int i = 0; i < 4; ++i) {
        h0.h[i] = (f16)n0[i]; l0.h[i] = (f16)(n0[i] - (float)h0.h[i]);
        h1.h[i] = (f16)n1[i]; l1.h[i] = (f16)(n1[i] - (float)h1.h[i]);
    }
    f16* ph = xh + (size_t)row * DIN;
    f16* pl = xl + (size_t)row * DIN;
    *(uint2*)(ph + 4 * lane)       = h0.u;
    *(uint2*)(ph + 256 + 4 * lane) = h1.u;
    *(uint2*)(pl + 4 * lane)       = l0.u;
    *(uint2*)(pl + 256 + 4 * lane) = l1.u;
}

// ---------------------------------------------------------------------------
// k_proj: QKV via split-fp16 MFMA (3 terms for q,k; 1 for v). grid (144,3).
// ---------------------------------------------------------------------------
__global__ __launch_bounds__(256) void k_proj(
    const f16* __restrict__ xh, const f16* __restrict__ xl,
    const float* __restrict__ Wq,  const float* __restrict__ Wk,  const float* __restrict__ Wv,
    const float* __restrict__ Wqs, const float* __restrict__ Wks, const float* __restrict__ Wvs,
    const float* __restrict__ Wqe, const float* __restrict__ Wke, const float* __restrict__ Wve,
    float* __restrict__ qf, float* __restrict__ kf, float* __restrict__ vf,
    f16* __restrict__ qsp, f16* __restrict__ ksp, f16* __restrict__ vhT)
{
    __shared__ f16 As[64 * 136];
    __shared__ f16 Bs[64 * 136];
    const int tid  = threadIdx.x;
    const int row0 = blockIdx.x * 64;
    const int rseq = row0 % L_;
    const int seg  = (rseq < S_) ? 0 : (rseq >= L_ - S_) ? 2 : 1;
    const int m    = blockIdx.y;
    const float* W;
    float* outf;
    if (m == 0)      { W = (seg == 0) ? Wqs : (seg == 2) ? Wqe : Wq; outf = qf; }
    else if (m == 1) { W = (seg == 0) ? Wks : (seg == 2) ? Wke : Wk; outf = kf; }
    else             { W = (seg == 0) ? Wvs : (seg == 2) ? Wve : Wv; outf = vf; }

    const int w = tid >> 6, lane = tid & 63;
    const int cl = lane & 15, quad = lane >> 4;
    const int r0 = 32 * (w >> 1), c0 = 32 * (w & 1);

    f32x4 acc[2][2];
    #pragma unroll
    for (int i = 0; i < 2; ++i)
        #pragma unroll
        for (int j = 0; j < 2; ++j) acc[i][j] = 0.f;

    for (int kc = 0; kc < DIN; kc += 64) {
        __syncthreads();
        #pragma unroll
        for (int i = 0; i < 2; ++i) {
            int g = tid + 256 * i;
            int r = g >> 3, c = g & 7;
            *(uint4*)(As + r * 136 + c * 8) =
                *(const uint4*)(xh + (size_t)(row0 + r) * DIN + kc + c * 8);
            *(uint4*)(As + r * 136 + 64 + c * 8) =
                *(const uint4*)(xl + (size_t)(row0 + r) * DIN + kc + c * 8);
        }
        #pragma unroll
        for (int i = 0; i < 4; ++i) {
            int g = tid + 256 * i;
            int k = g >> 4, c4 = g & 15;
            float4 wv = ((const float4*)W)[(size_t)(kc + k) * 16 + c4];
            f16 h0 = (f16)wv.x, h1 = (f16)wv.y, h2 = (f16)wv.z, h3 = (f16)wv.w;
            Bs[(c4 * 4 + 0) * 136 + k] = h0;
            Bs[(c4 * 4 + 1) * 136 + k] = h1;
            Bs[(c4 * 4 + 2) * 136 + k] = h2;
            Bs[(c4 * 4 + 3) * 136 + k] = h3;
            Bs[(c4 * 4 + 0) * 136 + 64 + k] = (f16)(wv.x - (float)h0);
            Bs[(c4 * 4 + 1) * 136 + 64 + k] = (f16)(wv.y - (float)h1);
            Bs[(c4 * 4 + 2) * 136 + 64 + k] = (f16)(wv.z - (float)h2);
            Bs[(c4 * 4 + 3) * 136 + 64 + k] = (f16)(wv.w - (float)h3);
        }
        __syncthreads();
        #pragma unroll
        for (int h = 0; h < 2; ++h) {
            half8 ah[2], al[2], bh[2], bl[2];
            #pragma unroll
            for (int rs = 0; rs < 2; ++rs) {
                const f16* base = As + (r0 + 16 * rs + cl) * 136 + h * 32 + quad * 8;
                ah[rs] = *(const half8*)(base);
                al[rs] = *(const half8*)(base + 64);
            }
            #pragma unroll
            for (int cs = 0; cs < 2; ++cs) {
                const f16* base = Bs + (c0 + 16 * cs + cl) * 136 + h * 32 + quad * 8;
                bh[cs] = *(const half8*)(base);
                bl[cs] = *(const half8*)(base + 64);
            }
            #pragma unroll
            for (int rs = 0; rs < 2; ++rs)
                #pragma unroll
                for (int cs = 0; cs < 2; ++cs) {
                    acc[rs][cs] = __builtin_amdgcn_mfma_f32_16x16x32_f16(ah[rs], bh[cs], acc[rs][cs], 0, 0, 0);
                    if (m < 2) {
                        acc[rs][cs] = __builtin_amdgcn_mfma_f32_16x16x32_f16(ah[rs], bl[cs], acc[rs][cs], 0, 0, 0);
                        acc[rs][cs] = __builtin_amdgcn_mfma_f32_16x16x32_f16(al[rs], bh[cs], acc[rs][cs], 0, 0, 0);
                    }
                }
        }
    }

    const int bI = row0 / L_;
    const int rb = row0 - bI * L_;
    f16* sp = (m == 0) ? qsp : ksp;
    #pragma unroll
    for (int rs = 0; rs < 2; ++rs)
        #pragma unroll
        for (int cs = 0; cs < 2; ++cs)
            #pragma unroll
            for (int r = 0; r < 4; ++r) {
                int lrow = r0 + 16 * rs + quad * 4 + r;
                int col  = c0 + 16 * cs + cl;
                float v  = acc[rs][cs][r];
                size_t grow = (size_t)(row0 + lrow);
                outf[grow * DK + col] = v;
                if (m < 2) {
                    f16 hv = (f16)v;
                    sp[grow * 128 + col]      = hv;
                    sp[grow * 128 + 64 + col] = (f16)(v - (float)hv);
                } else {
                    vhT[(size_t)(bI * 64 + col) * L_ + rb + lrow] = (f16)v;
                }
            }
}

// ---------------------------------------------------------------------------
// k_dots: D(fp32, visible chunks only) = Qmid . K^T via split-fp16 MFMA,
// plus per-(row,mid-chunk) gate sums G. grid (64, 34) x 256.
// ---------------------------------------------------------------------------
__global__ __launch_bounds__(256) void k_dots(
    const f16* __restrict__ qsp, const f16* __restrict__ ksp,
    float* __restrict__ D, float* __restrict__ G)
{
    __shared__ f16 Qs[128 * 136];
    __shared__ f16 Ks[64 * 136];
    const int tid  = threadIdx.x;
    const int gr0  = blockIdx.x * 128;
    const int by   = blockIdx.y;           // chunk 0..33 (0,1 = start keys)
    const int col0 = by * 64;
    const int b    = gr0 >> 11;
    const int q0   = gr0 & 2047;           // multiple of 128
    const size_t qrow0 = (size_t)b * L_ + S_ + q0;
    const size_t krow0 = (size_t)b * L_ + col0;

    #pragma unroll
    for (int i = 0; i < 8; ++i) {
        int g = tid + 256 * i;
        int r = g >> 4, c = g & 15;
        *(uint4*)(Qs + r * 136 + c * 8) = *(const uint4*)(qsp + (qrow0 + r) * 128 + c * 8);
    }
    #pragma unroll
    for (int i = 0; i < 4; ++i) {
        int g = tid + 256 * i;
        int r = g >> 4, c = g & 15;
        *(uint4*)(Ks + r * 136 + c * 8) = *(const uint4*)(ksp + (krow0 + r) * 128 + c * 8);
    }
    __syncthreads();

    const int w = tid >> 6, lane = tid & 63;
    const int cl = lane & 15, quad = lane >> 4;

    f32x4 acc[2][4];
    #pragma unroll
    for (int i = 0; i < 2; ++i)
        #pragma unroll
        for (int j = 0; j < 4; ++j) acc[i][j] = 0.f;

    #pragma unroll
    for (int h = 0; h < 2; ++h) {
        half8 ah[2], al[2], bh[4], bl[4];
        #pragma unroll
        for (int rs = 0; rs < 2; ++rs) {
            const f16* base = Qs + (32 * w + 16 * rs + cl) * 136 + h * 32 + quad * 8;
            ah[rs] = *(const half8*)(base);
            al[rs] = *(const half8*)(base + 64);
        }
        #pragma unroll
        for (int c = 0; c < 4; ++c) {
            const f16* base = Ks + (16 * c + cl) * 136 + h * 32 + quad * 8;
            bh[c] = *(const half8*)(base);
            bl[c] = *(const half8*)(base + 64);
        }
        #pragma unroll
        for (int rs = 0; rs < 2; ++rs)
            #pragma unroll
            for (int c = 0; c < 4; ++c) {
                acc[rs][c] = __builtin_amdgcn_mfma_f32_16x16x32_f16(ah[rs], bh[c], acc[rs][c], 0, 0, 0);
                acc[rs][c] = __builtin_amdgcn_mfma_f32_16x16x32_f16(ah[rs], bl[c], acc[rs][c], 0, 0, 0);
                acc[rs][c] = __builtin_amdgcn_mfma_f32_16x16x32_f16(al[rs], bh[c], acc[rs][c], 0, 0, 0);
            }
    }

    // D write only for visible chunks (start chunks always; mid chm <= q0/64+1)
    const bool writeD = (by < 2) || ((by - 2) <= (q0 >> 6) + 1);
    if (writeD) {
        #pragma unroll
        for (int rs = 0; rs < 2; ++rs)
            #pragma unroll
            for (int c = 0; c < 4; ++c)
                #pragma unroll
                for (int r = 0; r < 4; ++r) {
                    int mrow = gr0 + 32 * w + 16 * rs + quad * 4 + r;
                    int n    = col0 + 16 * c + cl;
                    D[(size_t)mrow * NCOLS + n] = acc[rs][c][r];
                }
    }
    // G for mid chunks (verified exact in round 9)
    if (by >= 2) {
        const int chm = by - 2;
        #pragma unroll
        for (int rs = 0; rs < 2; ++rs)
            #pragma unroll
            for (int r = 0; r < 4; ++r) {
                float s = 0.f;
                #pragma unroll
                for (int c = 0; c < 4; ++c)
                    s += 1.f / (1.f + __expf(-acc[rs][c][r]));
                #pragma unroll
                for (int off = 1; off < 16; off <<= 1) s += __shfl_xor(s, off);
                if (cl == 0)
                    G[(size_t)(gr0 + 32 * w + 16 * rs + quad * 4 + r) * 32 + chm] = s;
            }
    }
}

// ---------------------------------------------------------------------------
// k_scan: fused cope + gates(visible) + G-tail -> suffix scan -> CoPE bias ->
// softmax; writes fp16 P in place. grid 8192 x 256.
// ---------------------------------------------------------------------------
__global__ __launch_bounds__(256) void k_scan(
    const float* __restrict__ qf, const float* __restrict__ cope,
    const float* __restrict__ G, float* __restrict__ D)
{
    __shared__ float qv[DK];
    __shared__ float li[128];
    __shared__ float red[256];
    __shared__ float wtot[4];
    __shared__ float Gs[32];
    const int tid = threadIdx.x;
    const int gr  = blockIdx.x;
    const int b   = gr >> 11;
    const int q   = gr & 2047;
    const size_t grow = (size_t)b * L_ + S_ + q;
    const int qlim = (q & ~63) + 64;

    if (tid < 16) ((float4*)qv)[tid] = ((const float4*)qf)[grow * 16 + tid];
    if (tid >= 16 && tid < 24) ((float4*)Gs)[tid - 16] = ((const float4*)G)[(size_t)gr * 8 + tid - 16];
    __syncthreads();
    if (tid < 128) {
        float a = 0.f;
        #pragma unroll
        for (int d = 0; d < DK; ++d) a += qv[d] * cope[d * S_ + tid];
        li[tid] = a;
    }

    const float* Dr = D + (size_t)gr * NCOLS;
    const int j0 = tid * 8;
    float dot[8], gte[8];
    float csum = 0.f;
    if (j0 < qlim) {
        *(float4*)&dot[0] = *(const float4*)(Dr + 128 + j0);
        *(float4*)&dot[4] = *(const float4*)(Dr + 128 + j0 + 4);
        #pragma unroll
        for (int jj = 0; jj < 8; ++jj) {
            gte[jj] = 1.f / (1.f + __expf(-dot[jj]));
            csum += gte[jj];
        }
    } else {
        #pragma unroll
        for (int jj = 0; jj < 8; ++jj) { dot[jj] = 0.f; gte[jj] = 0.f; }
    }
    float sv = (tid < 128) ? Dr[tid] * SCALE : NEGINF;

    const int lane = tid & 63, wid = tid >> 6;
    float inc = csum;
    #pragma unroll
    for (int off = 1; off < 64; off <<= 1) {
        float u = __shfl_down(inc, off, 64);
        if (lane + off < 64) inc += u;
    }
    if (lane == 0) wtot[wid] = inc;
    __syncthreads();
    float wsuf = 0.f;
    #pragma unroll
    for (int w = 0; w < 4; ++w) if (w > wid) wsuf += wtot[w];
    // invisible-gate tail from G (chunks beyond qlim)
    float tail = 0.f;
    for (int c = (q >> 6) + 1; c < 32; ++c) tail += Gs[c];
    float run = inc - csum + wsuf + tail;    // exclusive suffix incl. tail

    float p8[8];
    #pragma unroll
    for (int jj = 7; jj >= 0; --jj) {
        run += gte[jj];
        float pos = fminf(run, (float)(S_ - 1));
        float pfl = floorf(pos);
        int ic  = (int)ceilf(pos);
        int ifl = (int)pfl;
        float w = pos - pfl;
        float bias = li[ic] * w + li[ifl] * (1.f - w);
        p8[jj] = (j0 + jj <= q) ? dot[jj] * SCALE + bias : NEGINF;
    }

    float mx = sv;
    #pragma unroll
    for (int jj = 0; jj < 8; ++jj) mx = fmaxf(mx, p8[jj]);
    red[tid] = mx;
    __syncthreads();
    for (int off = 128; off > 0; off >>= 1) {
        if (tid < off) red[tid] = fmaxf(red[tid], red[tid + off]);
        __syncthreads();
    }
    mx = red[0];
    __syncthreads();

    float lsum = 0.f;
    float e8[8];
    #pragma unroll
    for (int jj = 0; jj < 8; ++jj) {
        e8[jj] = __expf(p8[jj] - mx);
        lsum += e8[jj];
    }
    float es = 0.f;
    if (tid < 128) { es = __expf(sv - mx); lsum += es; }
    red[tid] = lsum;
    __syncthreads();
    for (int off = 128; off > 0; off >>= 1) {
        if (tid < off) red[tid] += red[tid + off];
        __syncthreads();
    }
    float inv = 1.f / red[0];

    f16* pb = (f16*)D + (size_t)gr * PROWS;
    if (j0 < qlim) {
        U4 o;
        #pragma unroll
        for (int jj = 0; jj < 8; ++jj) o.h[jj] = (f16)(e8[jj] * inv);
        *(uint4*)(pb + 128 + j0) = o.u;
    }
    if (tid < 128) pb[tid] = (f16)(es * inv);
}

// ---------------------------------------------------------------------------
// k_pv: O = P(fp16) @ V(fp16 transposed) via MFMA, 4-way K-split.
// grid (128, 4) x 256. (round-8 verified)
// ---------------------------------------------------------------------------
__global__ __launch_bounds__(256) void k_pv(
    const f16* __restrict__ Pb, const f16* __restrict__ vhT,
    float* __restrict__ Opart)
{
    __shared__ f16 Ps[64 * 72];
    __shared__ f16 Vt[64 * 72];
    const int tid = threadIdx.x;
    const int gr0 = blockIdx.x * 64;
    const int ks  = blockIdx.y;
    const int b   = gr0 >> 11, q0 = gr0 & 2047;
    const int cmax  = (191 + q0) >> 6;
    const int c_beg = ks * 9;
    int c_end = c_beg + 9;
    if (c_end > 34) c_end = 34;
    if (c_end > cmax + 1) c_end = cmax + 1;

    const int w = tid >> 6, lane = tid & 63;
    const int cl = lane & 15, quad = lane >> 4;
    f32x4 acc[4];
    #pragma unroll
    for (int c = 0; c < 4; ++c) acc[c] = 0.f;

    for (int ch = c_beg; ch < c_end; ++ch) {
        __syncthreads();
        #pragma unroll
        for (int i = 0; i < 2; ++i) {
            int g = tid + 256 * i;
            int r = g >> 3, c = g & 7;
            *(uint4*)(Ps + r * 72 + c * 8) =
                *(const uint4*)(Pb + (size_t)(gr0 + r) * PROWS + ch * 64 + c * 8);
            *(uint4*)(Vt + r * 72 + c * 8) =
                *(const uint4*)(vhT + (size_t)(b * 64 + r) * L_ + ch * 64 + c * 8);
        }
        __syncthreads();
        #pragma unroll
        for (int h = 0; h < 2; ++h) {
            half8 a = *(const half8*)(Ps + (16 * w + cl) * 72 + h * 32 + quad * 8);
            #pragma unroll
            for (int c = 0; c < 4; ++c) {
                half8 bv = *(const half8*)(Vt + (16 * c + cl) * 72 + h * 32 + quad * 8);
                acc[c] = __builtin_amdgcn_mfma_f32_16x16x32_f16(a, bv, acc[c], 0, 0, 0);
            }
        }
    }
    #pragma unroll
    for (int c = 0; c < 4; ++c)
        #pragma unroll
        for (int r = 0; r < 4; ++r) {
            int mrow = gr0 + 16 * w + quad * 4 + r;
            int n    = 16 * c + cl;
            Opart[((size_t)ks * NMID + mrow) * DK + n] = acc[c][r];
        }
}

// ---------------------------------------------------------------------------
// k_merge: out(mid rows) = sum of 4 partials. grid 2048 x 256.
// ---------------------------------------------------------------------------
__global__ __launch_bounds__(256) void k_merge(
    const float* __restrict__ Opart, float* __restrict__ out)
{
    const int e  = blockIdx.x * 256 + threadIdx.x;
    const int gr = e >> 6, c = e & 63;
    const int b  = gr >> 11, q = gr & 2047;
    const int NP = NMID * DK;
    float s = Opart[e] + Opart[e + NP] + Opart[e + 2 * NP] + Opart[e + 3 * NP];
    out[((size_t)b * L_ + S_ + q) * DK + c] = s;
}

// ---------------------------------------------------------------------------
// k_dots_edge: De = q_edge . k^T via split-fp16 MFMA. grid (8, 36) x 256.
// 128 q-rows x 64 key-cols per block; start-half needs only chunks 0-1.
// ---------------------------------------------------------------------------
__global__ __launch_bounds__(256) void k_dots_edge(
    const f16* __restrict__ qsp, const f16* __restrict__ ksp,
    float* __restrict__ De)
{
    const int bx   = blockIdx.x;
    const int b    = bx >> 1;
    const int half = bx & 1;
    const int by   = blockIdx.y;
    if (half == 0 && by > 1) return;

    __shared__ f16 Qs[128 * 136];
    __shared__ f16 Ks[64 * 136];
    const int tid = threadIdx.x;
    const int er0 = bx * 128;
    const size_t qrow0 = (size_t)b * L_ + (half ? 2176 : 0);
    const size_t krow0 = (size_t)b * L_ + by * 64;

    #pragma unroll
    for (int i = 0; i < 8; ++i) {
        int g = tid + 256 * i;
        int r = g >> 4, c = g & 15;
        *(uint4*)(Qs + r * 136 + c * 8) = *(const uint4*)(qsp + (qrow0 + r) * 128 + c * 8);
    }
    #pragma unroll
    for (int i = 0; i < 4; ++i) {
        int g = tid + 256 * i;
        int r = g >> 4, c = g & 15;
        *(uint4*)(Ks + r * 136 + c * 8) = *(const uint4*)(ksp + (krow0 + r) * 128 + c * 8);
    }
    __syncthreads();

    const int w = tid >> 6, lane = tid & 63;
    const int cl = lane & 15, quad = lane >> 4;

    f32x4 acc[2][4];
    #pragma unroll
    for (int i = 0; i < 2; ++i)
        #pragma unroll
        for (int j = 0; j < 4; ++j) acc[i][j] = 0.f;

    #pragma unroll
    for (int h = 0; h < 2; ++h) {
        half8 ah[2], al[2], bh[4], bl[4];
        #pragma unroll
        for (int rs = 0; rs < 2; ++rs) {
            const f16* base = Qs + (32 * w + 16 * rs + cl) * 136 + h * 32 + quad * 8;
            ah[rs] = *(const half8*)(base);
            al[rs] = *(const half8*)(base + 64);
        }
        #pragma unroll
        for (int c = 0; c < 4; ++c) {
            const f16* base = Ks + (16 * c + cl) * 136 + h * 32 + quad * 8;
            bh[c] = *(const half8*)(base);
            bl[c] = *(const half8*)(base + 64);
        }
        #pragma unroll
        for (int rs = 0; rs < 2; ++rs)
            #pragma unroll
            for (int c = 0; c < 4; ++c) {
                acc[rs][c] = __builtin_amdgcn_mfma_f32_16x16x32_f16(ah[rs], bh[c], acc[rs][c], 0, 0, 0);
                acc[rs][c] = __builtin_amdgcn_mfma_f32_16x16x32_f16(ah[rs], bl[c], acc[rs][c], 0, 0, 0);
                acc[rs][c] = __builtin_amdgcn_mfma_f32_16x16x32_f16(al[rs], bh[c], acc[rs][c], 0, 0, 0);
            }
    }

    #pragma unroll
    for (int rs = 0; rs < 2; ++rs)
        #pragma unroll
        for (int c = 0; c < 4; ++c)
            #pragma unroll
            for (int r = 0; r < 4; ++r) {
                int erow = er0 + 32 * w + 16 * rs + quad * 4 + r;
                int n    = by * 64 + 16 * c + cl;
                De[(size_t)erow * LE + n] = acc[rs][c][r];
            }
}

// ---------------------------------------------------------------------------
// k_soft_edge: row-wise causal softmax; writes fp16 Pe in place. grid 1024.
// ---------------------------------------------------------------------------
__global__ __launch_bounds__(256) void k_soft_edge(float* __restrict__ De)
{
    __shared__ float red[256];
    const int tid = threadIdx.x;
    const int er  = blockIdx.x;
    const int r   = er & 255;
    const int Q   = (r < 128) ? r : (2048 + r);
    const size_t rowoff = (size_t)er * LE;

    float v[9];
    #pragma unroll
    for (int i = 0; i < 9; ++i) {
        int j = tid + 256 * i;
        float d = De[rowoff + j];
        v[i] = (j <= Q) ? d * SCALE : NEGINF;
    }
    float mx = v[0];
    #pragma unroll
    for (int i = 1; i < 9; ++i) mx = fmaxf(mx, v[i]);
    red[tid] = mx;
    __syncthreads();
    for (int off = 128; off > 0; off >>= 1) {
        if (tid < off) red[tid] = fmaxf(red[tid], red[tid + off]);
        __syncthreads();
    }
    mx = red[0];
    __syncthreads();

    float lsum = 0.f;
    #pragma unroll
    for (int i = 0; i < 9; ++i) {
        v[i] = __expf(v[i] - mx);
        lsum += v[i];
    }
    red[tid] = lsum;
    __syncthreads();
    for (int off = 128; off > 0; off >>= 1) {
        if (tid < off) red[tid] += red[tid + off];
        __syncthreads();
    }
    float inv = 1.f / red[0];
    f16* pe = (f16*)De + (size_t)er * PEPITCH;
    #pragma unroll
    for (int i = 0; i < 9; ++i)
        pe[tid + 256 * i] = (f16)(v[i] * inv);
}

// ---------------------------------------------------------------------------
// k_pv_edge: Oe = Pe(fp16) @ V(fp16 T) via MFMA, 8-way K-split. grid (16,8).
// ---------------------------------------------------------------------------
__global__ __launch_bounds__(256) void k_pv_edge(
    const f16* __restrict__ Pe, const f16* __restrict__ vhT,
    float* __restrict__ Oe)
{
    __shared__ f16 Ps[64 * 72];
    __shared__ f16 Vt[64 * 72];
    const int tid = threadIdx.x;
    const int er0 = blockIdx.x * 64;
    const int ks  = blockIdx.y;
    const int b   = er0 >> 8, r0 = er0 & 255;
    const int Qmax = (r0 < 128) ? (r0 + 63) : (2048 + r0 + 63);
    const int cmax = Qmax >> 6;
    const int c_beg = ks * 5;
    int c_end = c_beg + 5;
    if (c_end > 36) c_end = 36;
    if (c_end > cmax + 1) c_end = cmax + 1;

    const int w = tid >> 6, lane = tid & 63;
    const int cl = lane & 15, quad = lane >> 4;
    f32x4 acc[4];
    #pragma unroll
    for (int c = 0; c < 4; ++c) acc[c] = 0.f;

    for (int ch = c_beg; ch < c_end; ++ch) {
        __syncthreads();
        #pragma unroll
        for (int i = 0; i < 2; ++i) {
            int g = tid + 256 * i;
            int r = g >> 3, c = g & 7;
            *(uint4*)(Ps + r * 72 + c * 8) =
                *(const uint4*)(Pe + (size_t)(er0 + r) * PEPITCH + ch * 64 + c * 8);
            *(uint4*)(Vt + r * 72 + c * 8) =
                *(const uint4*)(vhT + (size_t)(b * 64 + r) * L_ + ch * 64 + c * 8);
        }
        __syncthreads();
        #pragma unroll
        for (int h = 0; h < 2; ++h) {
            half8 a = *(const half8*)(Ps + (16 * w + cl) * 72 + h * 32 + quad * 8);
            #pragma unroll
            for (int c = 0; c < 4; ++c) {
                half8 bv = *(const half8*)(Vt + (16 * c + cl) * 72 + h * 32 + quad * 8);
                acc[c] = __builtin_amdgcn_mfma_f32_16x16x32_f16(a, bv, acc[c], 0, 0, 0);
            }
        }
    }
    #pragma unroll
    for (int c = 0; c < 4; ++c)
        #pragma unroll
        for (int r = 0; r < 4; ++r) {
            int erow = er0 + 16 * w + quad * 4 + r;
            int n    = 16 * c + cl;
            Oe[((size_t)ks * NEDGE + erow) * DK + n] = acc[c][r];
        }
}

// ---------------------------------------------------------------------------
// k_merge_edge: out(edge rows) = sum of 8 partials. grid 256 x 256.
// ---------------------------------------------------------------------------
__global__ __launch_bounds__(256) void k_merge_edge(
    const float* __restrict__ Oe, float* __restrict__ out)
{
    const int e  = blockIdx.x * 256 + threadIdx.x;
    const int er = e >> 6, c = e & 63;
    const int b  = er >> 8, r = er & 255;
    const int gQ = (r < 128) ? r : (2048 + r);
    const int NP = NEDGE * DK;
    float s = 0.f;
    #pragma unroll
    for (int i = 0; i < 8; ++i) s += Oe[e + i * NP];
    out[((size_t)b * L_ + gQ) * DK + c] = s;
}

// ---------------------------------------------------------------------------
extern "C" void kernel_launch(void* const* d_in, const int* in_sizes, int n_in,
                              void* d_out, int out_size, void* d_ws, size_t ws_size,
                              hipStream_t stream)
{
    const float* x    = (const float*)d_in[0];
    const float* Wq   = (const float*)d_in[1];
    const float* Wk   = (const float*)d_in[2];
    const float* Wv   = (const float*)d_in[3];
    const float* Wqs  = (const float*)d_in[4];
    const float* Wks  = (const float*)d_in[5];
    const float* Wvs  = (const float*)d_in[6];
    const float* Wqe  = (const float*)d_in[7];
    const float* Wke  = (const float*)d_in[8];
    const float* Wve  = (const float*)d_in[9];
    const float* g0   = (const float*)d_in[10];
    const float* b0   = (const float*)d_in[11];
    const float* gs   = (const float*)d_in[12];
    const float* bs   = (const float*)d_in[13];
    const float* ge   = (const float*)d_in[14];
    const float* be   = (const float*)d_in[15];
    const float* cope = (const float*)d_in[16];

    const size_t NR = (size_t)B_ * L_;               // 9216 rows
    float* ws = (float*)d_ws;
    float* qf    = ws;                               // 9216*64 f32
    float* kf    = qf + NR * DK;
    float* vf    = kf + NR * DK;
    float* Opart = vf + NR * DK;                     // 8*1024*64 & 4*8192*64 f32 region
    float* G     = Opart + (size_t)4 * NMID * DK;    // 8192*32 f32
    f16*   qsp   = (f16*)(G + (size_t)NMID * 32);    // 9216*128 h (hi|lo)
    f16*   ksp   = qsp + NR * 128;
    f16*   vhT   = ksp + NR * 128;                   // 4*64*2304 h
    float* D     = (float*)(vhT + NR * DK);          // 8192*2176 f32
    // xh/xl live INSIDE D's region (dead before k_dots writes D)
    f16*   xh    = (f16*)D;                          // 9216*512 h
    f16*   xl    = xh + NR * DIN;                    // 9216*512 h
    float* De    = D;                                // edge reuses D after k_pv
    float* Oe    = Opart;                            // edge reuses Opart after k_merge
    float* out   = (float*)d_out;

    k_ln  <<<L_ * B_ / 4, 256, 0, stream>>>(x, g0, b0, gs, bs, ge, be, xh, xl);
    k_proj<<<dim3(144, 3), 256, 0, stream>>>(xh, xl, Wq, Wk, Wv, Wqs, Wks, Wvs,
                                             Wqe, Wke, Wve, qf, kf, vf,
                                             qsp, ksp, vhT);
    k_dots<<<dim3(NMID / 128, 34), 256, 0, stream>>>(qsp, ksp, D, G);
    k_scan<<<NMID, 256, 0, stream>>>(qf, cope, G, D);
    k_pv  <<<dim3(NMID / 64, 4), 256, 0, stream>>>((const f16*)D, vhT, Opart);
    k_merge<<<NMID * DK / 256, 256, 0, stream>>>(Opart, out);
    // edge path (reuses D's memory after k_pv, Opart after k_merge)
    k_dots_edge<<<dim3(8, 36), 256, 0, stream>>>(qsp, ksp, De);
    k_soft_edge<<<NEDGE, 256, 0, stream>>>(De);
    k_pv_edge<<<dim3(NEDGE / 64, 8), 256, 0, stream>>>((const f16*)De, vhT, Oe);
    k_merge_edge<<<NEDGE * DK / 256, 256, 0, stream>>>(Oe, out);
}

// Round 11
// 201.707 us; speedup vs baseline: 1.2824x; 1.1066x over previous
//
#include <hip/hip_runtime.h>
#include <math.h>

#define B_    4
#define SEQ_  2048
#define S_    128
#define L_    2304          // SEQ + 2*S
#define DIN   512
#define DK    64
#define NEGINF (-1e30f)
#define SCALE 0.125f
#define NCOLS 2176          // start(128) + mid(2048) key columns in D
#define NMID  8192          // B_*SEQ_
#define NEDGE 1024          // B_*2*S_
#define LE    2304          // edge De row length (f32)
#define PROWS 4352          // fp16 pitch inside an fp32 D row
#define PEPITCH 4608        // fp16 pitch inside an fp32 De row

typedef _Float16 f16;
typedef __attribute__((ext_vector_type(8))) _Float16 half8;
typedef __attribute__((ext_vector_type(4))) float f32x4;

union U4 { uint4 u; f16 h[8]; };

// ---------------------------------------------------------------------------
// k_proj: fused LayerNorm + QKV via split-fp16 MFMA (3 terms q,k; 1 term v).
// grid (144, 3) x 256. Emits split-fp16 q/k and transposed fp16 V only.
// ---------------------------------------------------------------------------
__global__ __launch_bounds__(256) void k_proj(
    const float* __restrict__ x,
    const float* __restrict__ Wq,  const float* __restrict__ Wk,  const float* __restrict__ Wv,
    const float* __restrict__ Wqs, const float* __restrict__ Wks, const float* __restrict__ Wvs,
    const float* __restrict__ Wqe, const float* __restrict__ Wke, const float* __restrict__ Wve,
    const float* __restrict__ g0, const float* __restrict__ b0,
    const float* __restrict__ gs, const float* __restrict__ bs,
    const float* __restrict__ ge, const float* __restrict__ be,
    f16* __restrict__ qsp, f16* __restrict__ ksp, f16* __restrict__ vhT)
{
    __shared__ f16 As[64 * 136];   // [row][hi 0..63 | lo 64..127 | pad]
    __shared__ f16 Bs[64 * 136];
    __shared__ float mean_s[64], rstd_s[64];
    const int tid  = threadIdx.x;
    const int row0 = blockIdx.x * 64;
    const int rseq = row0 % L_;
    const int seg  = (rseq < S_) ? 0 : (rseq >= L_ - S_) ? 2 : 1;
    const int m    = blockIdx.y;
    const float* W;
    if (m == 0)      W = (seg == 0) ? Wqs : (seg == 2) ? Wqe : Wq;
    else if (m == 1) W = (seg == 0) ? Wks : (seg == 2) ? Wke : Wk;
    else             W = (seg == 0) ? Wvs : (seg == 2) ? Wve : Wv;
    const float* gg = (seg == 0) ? gs : (seg == 2) ? ge : g0;
    const float* bb = (seg == 0) ? bs : (seg == 2) ? be : b0;

    // row stats: 4 threads per row, 128 elems each
    {
        const int rr = tid >> 2, qq = tid & 3;
        const float4* xr = (const float4*)(x + (size_t)(row0 + rr) * DIN) + qq * 32;
        float s = 0.f, s2 = 0.f;
        #pragma unroll
        for (int i = 0; i < 32; ++i) {
            float4 v = xr[i];
            s  += v.x + v.y + v.z + v.w;
            s2 += v.x * v.x + v.y * v.y + v.z * v.z + v.w * v.w;
        }
        s  += __shfl_xor(s, 1);  s  += __shfl_xor(s, 2);
        s2 += __shfl_xor(s2, 1); s2 += __shfl_xor(s2, 2);
        if (qq == 0) {
            float mean = s * (1.f / DIN);
            mean_s[rr] = mean;
            rstd_s[rr] = rsqrtf(s2 * (1.f / DIN) - mean * mean + 1e-5f);
        }
    }

    const int w = tid >> 6, lane = tid & 63;
    const int cl = lane & 15, quad = lane >> 4;
    const int r0 = 32 * (w >> 1), c0 = 32 * (w & 1);

    f32x4 acc[2][2];
    #pragma unroll
    for (int i = 0; i < 2; ++i)
        #pragma unroll
        for (int j = 0; j < 2; ++j) acc[i][j] = 0.f;

    for (int kc = 0; kc < DIN; kc += 64) {
        __syncthreads();
        // As: LN-on-the-fly + hi/lo split
        #pragma unroll
        for (int i = 0; i < 2; ++i) {
            int g = tid + 256 * i;           // 0..511: (row, 8-col group)
            int r = g >> 3, c8 = g & 7;
            const float* xp = x + (size_t)(row0 + r) * DIN + kc + c8 * 8;
            float4 a0 = *(const float4*)xp;
            float4 a1 = *(const float4*)(xp + 4);
            float4 gA = *(const float4*)(gg + kc + c8 * 8);
            float4 gB = *(const float4*)(gg + kc + c8 * 8 + 4);
            float4 bA = *(const float4*)(bb + kc + c8 * 8);
            float4 bB = *(const float4*)(bb + kc + c8 * 8 + 4);
            float mean = mean_s[r], rstd = rstd_s[r];
            float n[8];
            n[0] = (a0.x - mean) * rstd * gA.x + bA.x;
            n[1] = (a0.y - mean) * rstd * gA.y + bA.y;
            n[2] = (a0.z - mean) * rstd * gA.z + bA.z;
            n[3] = (a0.w - mean) * rstd * gA.w + bA.w;
            n[4] = (a1.x - mean) * rstd * gB.x + bB.x;
            n[5] = (a1.y - mean) * rstd * gB.y + bB.y;
            n[6] = (a1.z - mean) * rstd * gB.z + bB.z;
            n[7] = (a1.w - mean) * rstd * gB.w + bB.w;
            U4 hi, lo;
            #pragma unroll
            for (int j = 0; j < 8; ++j) {
                hi.h[j] = (f16)n[j];
                lo.h[j] = (f16)(n[j] - (float)hi.h[j]);
            }
            *(uint4*)(As + r * 136 + c8 * 8)      = hi.u;
            *(uint4*)(As + r * 136 + 64 + c8 * 8) = lo.u;
        }
        // Bs: weights, hi/lo split (transposed)
        #pragma unroll
        for (int i = 0; i < 4; ++i) {
            int g = tid + 256 * i;
            int k = g >> 4, c4 = g & 15;
            float4 wv = ((const float4*)W)[(size_t)(kc + k) * 16 + c4];
            f16 h0 = (f16)wv.x, h1 = (f16)wv.y, h2 = (f16)wv.z, h3 = (f16)wv.w;
            Bs[(c4 * 4 + 0) * 136 + k] = h0;
            Bs[(c4 * 4 + 1) * 136 + k] = h1;
            Bs[(c4 * 4 + 2) * 136 + k] = h2;
            Bs[(c4 * 4 + 3) * 136 + k] = h3;
            Bs[(c4 * 4 + 0) * 136 + 64 + k] = (f16)(wv.x - (float)h0);
            Bs[(c4 * 4 + 1) * 136 + 64 + k] = (f16)(wv.y - (float)h1);
            Bs[(c4 * 4 + 2) * 136 + 64 + k] = (f16)(wv.z - (float)h2);
            Bs[(c4 * 4 + 3) * 136 + 64 + k] = (f16)(wv.w - (float)h3);
        }
        __syncthreads();
        #pragma unroll
        for (int h = 0; h < 2; ++h) {
            half8 ah[2], al[2], bh[2], bl[2];
            #pragma unroll
            for (int rs = 0; rs < 2; ++rs) {
                const f16* base = As + (r0 + 16 * rs + cl) * 136 + h * 32 + quad * 8;
                ah[rs] = *(const half8*)(base);
                al[rs] = *(const half8*)(base + 64);
            }
            #pragma unroll
            for (int cs = 0; cs < 2; ++cs) {
                const f16* base = Bs + (c0 + 16 * cs + cl) * 136 + h * 32 + quad * 8;
                bh[cs] = *(const half8*)(base);
                bl[cs] = *(const half8*)(base + 64);
            }
            #pragma unroll
            for (int rs = 0; rs < 2; ++rs)
                #pragma unroll
                for (int cs = 0; cs < 2; ++cs) {
                    acc[rs][cs] = __builtin_amdgcn_mfma_f32_16x16x32_f16(ah[rs], bh[cs], acc[rs][cs], 0, 0, 0);
                    if (m < 2) {
                        acc[rs][cs] = __builtin_amdgcn_mfma_f32_16x16x32_f16(ah[rs], bl[cs], acc[rs][cs], 0, 0, 0);
                        acc[rs][cs] = __builtin_amdgcn_mfma_f32_16x16x32_f16(al[rs], bh[cs], acc[rs][cs], 0, 0, 0);
                    }
                }
        }
    }

    const int bI = row0 / L_;
    const int rb = row0 - bI * L_;
    f16* sp = (m == 0) ? qsp : ksp;
    #pragma unroll
    for (int rs = 0; rs < 2; ++rs)
        #pragma unroll
        for (int cs = 0; cs < 2; ++cs)
            #pragma unroll
            for (int r = 0; r < 4; ++r) {
                int lrow = r0 + 16 * rs + quad * 4 + r;
                int col  = c0 + 16 * cs + cl;
                float v  = acc[rs][cs][r];
                size_t grow = (size_t)(row0 + lrow);
                if (m < 2) {
                    f16 hv = (f16)v;
                    sp[grow * 128 + col]      = hv;
                    sp[grow * 128 + 64 + col] = (f16)(v - (float)hv);
                } else {
                    vhT[(size_t)(bI * 64 + col) * L_ + rb + lrow] = (f16)v;
                }
            }
}

// ---------------------------------------------------------------------------
// k_dots: mid + edge dots via split-fp16 MFMA. grid (72, 36) x 256.
// bx<64: mid (D visible chunks + G gate sums). bx>=64: edge (De).
// ---------------------------------------------------------------------------
__global__ __launch_bounds__(256) void k_dots(
    const f16* __restrict__ qsp, const f16* __restrict__ ksp,
    float* __restrict__ D, float* __restrict__ G, float* __restrict__ De)
{
    const int bx = blockIdx.x, by = blockIdx.y;
    const bool edge = (bx >= 64);
    int b, q0 = 0;
    size_t qrow0;
    if (!edge) {
        if (by >= 34) return;
        b = bx >> 4;
        q0 = (bx * 128) & 2047;
        qrow0 = (size_t)b * L_ + S_ + q0;
    } else {
        int ex = bx - 64;
        b = ex >> 1;
        int half = ex & 1;
        if (half == 0 && by > 1) return;      // start rows see only cols <128
        qrow0 = (size_t)b * L_ + (half ? 2176 : 0);
    }
    const int col0 = by * 64;
    const size_t krow0 = (size_t)b * L_ + col0;

    __shared__ f16 Qs[128 * 136];
    __shared__ f16 Ks[64 * 136];
    const int tid = threadIdx.x;

    #pragma unroll
    for (int i = 0; i < 8; ++i) {
        int g = tid + 256 * i;
        int r = g >> 4, c = g & 15;
        *(uint4*)(Qs + r * 136 + c * 8) = *(const uint4*)(qsp + (qrow0 + r) * 128 + c * 8);
    }
    #pragma unroll
    for (int i = 0; i < 4; ++i) {
        int g = tid + 256 * i;
        int r = g >> 4, c = g & 15;
        *(uint4*)(Ks + r * 136 + c * 8) = *(const uint4*)(ksp + (krow0 + r) * 128 + c * 8);
    }
    __syncthreads();

    const int w = tid >> 6, lane = tid & 63;
    const int cl = lane & 15, quad = lane >> 4;

    f32x4 acc[2][4];
    #pragma unroll
    for (int i = 0; i < 2; ++i)
        #pragma unroll
        for (int j = 0; j < 4; ++j) acc[i][j] = 0.f;

    #pragma unroll
    for (int h = 0; h < 2; ++h) {
        half8 ah[2], al[2], bh[4], bl[4];
        #pragma unroll
        for (int rs = 0; rs < 2; ++rs) {
            const f16* base = Qs + (32 * w + 16 * rs + cl) * 136 + h * 32 + quad * 8;
            ah[rs] = *(const half8*)(base);
            al[rs] = *(const half8*)(base + 64);
        }
        #pragma unroll
        for (int c = 0; c < 4; ++c) {
            const f16* base = Ks + (16 * c + cl) * 136 + h * 32 + quad * 8;
            bh[c] = *(const half8*)(base);
            bl[c] = *(const half8*)(base + 64);
        }
        #pragma unroll
        for (int rs = 0; rs < 2; ++rs)
            #pragma unroll
            for (int c = 0; c < 4; ++c) {
                acc[rs][c] = __builtin_amdgcn_mfma_f32_16x16x32_f16(ah[rs], bh[c], acc[rs][c], 0, 0, 0);
                acc[rs][c] = __builtin_amdgcn_mfma_f32_16x16x32_f16(ah[rs], bl[c], acc[rs][c], 0, 0, 0);
                acc[rs][c] = __builtin_amdgcn_mfma_f32_16x16x32_f16(al[rs], bh[c], acc[rs][c], 0, 0, 0);
            }
    }

    if (!edge) {
        const int gr0 = bx * 128;
        const bool writeD = (by < 2) || ((by - 2) <= (q0 >> 6) + 1);
        if (writeD) {
            #pragma unroll
            for (int rs = 0; rs < 2; ++rs)
                #pragma unroll
                for (int c = 0; c < 4; ++c)
                    #pragma unroll
                    for (int r = 0; r < 4; ++r) {
                        int mrow = gr0 + 32 * w + 16 * rs + quad * 4 + r;
                        int n    = col0 + 16 * c + cl;
                        D[(size_t)mrow * NCOLS + n] = acc[rs][c][r];
                    }
        }
        if (by >= 2) {
            const int chm = by - 2;
            #pragma unroll
            for (int rs = 0; rs < 2; ++rs)
                #pragma unroll
                for (int r = 0; r < 4; ++r) {
                    float s = 0.f;
                    #pragma unroll
                    for (int c = 0; c < 4; ++c)
                        s += 1.f / (1.f + __expf(-acc[rs][c][r]));
                    #pragma unroll
                    for (int off = 1; off < 16; off <<= 1) s += __shfl_xor(s, off);
                    if (cl == 0)
                        G[(size_t)(gr0 + 32 * w + 16 * rs + quad * 4 + r) * 32 + chm] = s;
                }
        }
    } else {
        const int er0 = (bx - 64) * 128;
        #pragma unroll
        for (int rs = 0; rs < 2; ++rs)
            #pragma unroll
            for (int c = 0; c < 4; ++c)
                #pragma unroll
                for (int r = 0; r < 4; ++r) {
                    int erow = er0 + 32 * w + 16 * rs + quad * 4 + r;
                    int n    = col0 + 16 * c + cl;
                    De[(size_t)erow * LE + n] = acc[rs][c][r];
                }
    }
}

// ---------------------------------------------------------------------------
// k_scan: grid 9216 x 256. gr<8192: mid row (cope + gates + G-tail suffix +
// softmax -> fp16 P in D). gr>=8192: edge row causal softmax -> fp16 Pe in De.
// ---------------------------------------------------------------------------
__global__ __launch_bounds__(256) void k_scan(
    const f16* __restrict__ qsp, const float* __restrict__ cope,
    const float* __restrict__ G, float* __restrict__ D, float* __restrict__ De)
{
    __shared__ f16   qvh[128];
    __shared__ float li[128];
    __shared__ float Gs[32];
    __shared__ float wtot[4], wmax[4], wsum[4];
    const int tid = threadIdx.x;
    const int gr  = blockIdx.x;
    const int lane = tid & 63, wid = tid >> 6;

    if (gr < NMID) {
        const int b = gr >> 11;
        const int q = gr & 2047;
        const size_t grow = (size_t)b * L_ + S_ + q;
        const int qlim = (q & ~63) + 64;

        if (tid < 16) ((uint4*)qvh)[tid] = ((const uint4*)(qsp + grow * 128))[tid];
        if (tid >= 16 && tid < 24)
            ((float4*)Gs)[tid - 16] = ((const float4*)G)[(size_t)gr * 8 + tid - 16];
        __syncthreads();
        if (tid < 128) {
            float a = 0.f;
            #pragma unroll
            for (int d = 0; d < DK; ++d)
                a += ((float)qvh[d] + (float)qvh[64 + d]) * cope[d * S_ + tid];
            li[tid] = a;
        }

        const float* Dr = D + (size_t)gr * NCOLS;
        const int j0 = tid * 8;
        float dot[8], gte[8];
        float csum = 0.f;
        if (j0 < qlim) {
            *(float4*)&dot[0] = *(const float4*)(Dr + 128 + j0);
            *(float4*)&dot[4] = *(const float4*)(Dr + 128 + j0 + 4);
            #pragma unroll
            for (int jj = 0; jj < 8; ++jj) {
                gte[jj] = 1.f / (1.f + __expf(-dot[jj]));
                csum += gte[jj];
            }
        } else {
            #pragma unroll
            for (int jj = 0; jj < 8; ++jj) { dot[jj] = 0.f; gte[jj] = 0.f; }
        }
        float sv = (tid < 128) ? Dr[tid] * SCALE : NEGINF;

        // wave suffix scan of chunk sums
        float inc = csum;
        #pragma unroll
        for (int off = 1; off < 64; off <<= 1) {
            float u = __shfl_down(inc, off, 64);
            if (lane + off < 64) inc += u;
        }
        if (lane == 0) wtot[wid] = inc;
        __syncthreads();                 // also publishes li
        float wsuf = 0.f;
        #pragma unroll
        for (int w = 0; w < 4; ++w) if (w > wid) wsuf += wtot[w];
        float tail = 0.f;
        for (int c = (q >> 6) + 1; c < 32; ++c) tail += Gs[c];
        float run = inc - csum + wsuf + tail;

        float p8[8];
        #pragma unroll
        for (int jj = 7; jj >= 0; --jj) {
            run += gte[jj];
            float pos = fminf(run, (float)(S_ - 1));
            float pfl = floorf(pos);
            int ic  = (int)ceilf(pos);
            int ifl = (int)pfl;
            float w = pos - pfl;
            float bias = li[ic] * w + li[ifl] * (1.f - w);
            p8[jj] = (j0 + jj <= q) ? dot[jj] * SCALE + bias : NEGINF;
        }

        float mx = sv;
        #pragma unroll
        for (int jj = 0; jj < 8; ++jj) mx = fmaxf(mx, p8[jj]);
        #pragma unroll
        for (int off = 1; off < 64; off <<= 1) mx = fmaxf(mx, __shfl_xor(mx, off));
        if (lane == 0) wmax[wid] = mx;
        __syncthreads();
        mx = fmaxf(fmaxf(wmax[0], wmax[1]), fmaxf(wmax[2], wmax[3]));

        float lsum = 0.f;
        float e8[8];
        #pragma unroll
        for (int jj = 0; jj < 8; ++jj) {
            e8[jj] = __expf(p8[jj] - mx);
            lsum += e8[jj];
        }
        float es = 0.f;
        if (tid < 128) { es = __expf(sv - mx); lsum += es; }
        #pragma unroll
        for (int off = 1; off < 64; off <<= 1) lsum += __shfl_xor(lsum, off);
        if (lane == 0) wsum[wid] = lsum;
        __syncthreads();
        float inv = 1.f / (wsum[0] + wsum[1] + wsum[2] + wsum[3]);

        f16* pb = (f16*)D + (size_t)gr * PROWS;
        if (j0 < qlim) {
            U4 o;
            #pragma unroll
            for (int jj = 0; jj < 8; ++jj) o.h[jj] = (f16)(e8[jj] * inv);
            *(uint4*)(pb + 128 + j0) = o.u;
        }
        if (tid < 128) pb[tid] = (f16)(es * inv);
    } else {
        // edge row softmax
        const int er = gr - NMID;
        const int r  = er & 255;
        const int Q  = (r < 128) ? r : (2048 + r);
        const size_t rowoff = (size_t)er * LE;

        float v[9];
        #pragma unroll
        for (int i = 0; i < 9; ++i) {
            int j = tid + 256 * i;
            float d = De[rowoff + j];
            v[i] = (j <= Q) ? d * SCALE : NEGINF;
        }
        float mx = v[0];
        #pragma unroll
        for (int i = 1; i < 9; ++i) mx = fmaxf(mx, v[i]);
        #pragma unroll
        for (int off = 1; off < 64; off <<= 1) mx = fmaxf(mx, __shfl_xor(mx, off));
        if (lane == 0) wmax[wid] = mx;
        __syncthreads();
        mx = fmaxf(fmaxf(wmax[0], wmax[1]), fmaxf(wmax[2], wmax[3]));

        float lsum = 0.f;
        #pragma unroll
        for (int i = 0; i < 9; ++i) {
            v[i] = __expf(v[i] - mx);
            lsum += v[i];
        }
        #pragma unroll
        for (int off = 1; off < 64; off <<= 1) lsum += __shfl_xor(lsum, off);
        if (lane == 0) wsum[wid] = lsum;
        __syncthreads();
        float inv = 1.f / (wsum[0] + wsum[1] + wsum[2] + wsum[3]);

        f16* pe = (f16*)De + (size_t)er * PEPITCH;
        #pragma unroll
        for (int i = 0; i < 9; ++i)
            pe[tid + 256 * i] = (f16)(v[i] * inv);
    }
}

// ---------------------------------------------------------------------------
// k_pv: mid + edge PV via fp16 MFMA, 4-way K-split. grid (144, 4) x 256.
// bx<128: mid (P in D, out Opart). bx>=128: edge (Pe in De, out Oe).
// ---------------------------------------------------------------------------
__global__ __launch_bounds__(256) void k_pv(
    const f16* __restrict__ Pmid, const f16* __restrict__ Pedge,
    const f16* __restrict__ vhT,
    float* __restrict__ Opart, float* __restrict__ Oe)
{
    __shared__ f16 Ps[64 * 72];
    __shared__ f16 Vt[64 * 72];
    const int tid = threadIdx.x;
    const int bx  = blockIdx.x;
    const int ks  = blockIdx.y;
    const bool edge = (bx >= 128);

    const f16* Pb;
    size_t pitch;
    int row0, b, cap, cmax;
    float* outp;
    if (!edge) {
        row0 = bx * 64;
        b = row0 >> 11;
        int q0 = row0 & 2047;
        Pb = Pmid; pitch = PROWS; cap = 34;
        cmax = (191 + q0) >> 6;
        outp = Opart + (size_t)ks * NMID * DK;
    } else {
        row0 = (bx - 128) * 64;
        b = row0 >> 8;
        int r0 = row0 & 255;
        Pb = Pedge; pitch = PEPITCH; cap = 36;
        int Qmax = (r0 < 128) ? (r0 + 63) : (2048 + r0 + 63);
        cmax = Qmax >> 6;
        outp = Oe + (size_t)ks * NEDGE * DK;
    }
    const int c_beg = ks * 9;
    int c_end = c_beg + 9;
    if (c_end > cap) c_end = cap;
    if (c_end > cmax + 1) c_end = cmax + 1;

    const int w = tid >> 6, lane = tid & 63;
    const int cl = lane & 15, quad = lane >> 4;
    f32x4 acc[4];
    #pragma unroll
    for (int c = 0; c < 4; ++c) acc[c] = 0.f;

    for (int ch = c_beg; ch < c_end; ++ch) {
        __syncthreads();
        #pragma unroll
        for (int i = 0; i < 2; ++i) {
            int g = tid + 256 * i;
            int r = g >> 3, c = g & 7;
            *(uint4*)(Ps + r * 72 + c * 8) =
                *(const uint4*)(Pb + (size_t)(row0 + r) * pitch + ch * 64 + c * 8);
            *(uint4*)(Vt + r * 72 + c * 8) =
                *(const uint4*)(vhT + (size_t)(b * 64 + r) * L_ + ch * 64 + c * 8);
        }
        __syncthreads();
        #pragma unroll
        for (int h = 0; h < 2; ++h) {
            half8 a = *(const half8*)(Ps + (16 * w + cl) * 72 + h * 32 + quad * 8);
            #pragma unroll
            for (int c = 0; c < 4; ++c) {
                half8 bv = *(const half8*)(Vt + (16 * c + cl) * 72 + h * 32 + quad * 8);
                acc[c] = __builtin_amdgcn_mfma_f32_16x16x32_f16(a, bv, acc[c], 0, 0, 0);
            }
        }
    }
    #pragma unroll
    for (int c = 0; c < 4; ++c)
        #pragma unroll
        for (int r = 0; r < 4; ++r) {
            int mrow = row0 + 16 * w + quad * 4 + r;
            int n    = 16 * c + cl;
            outp[(size_t)mrow * DK + n] = acc[c][r];
        }
}

// ---------------------------------------------------------------------------
// k_merge: sum 4 partials, mid + edge. grid 2304 x 256.
// ---------------------------------------------------------------------------
__global__ __launch_bounds__(256) void k_merge(
    const float* __restrict__ Opart, const float* __restrict__ Oe,
    float* __restrict__ out)
{
    const int e = blockIdx.x * 256 + threadIdx.x;
    if (e < NMID * DK) {
        const int gr = e >> 6, c = e & 63;
        const int b  = gr >> 11, q = gr & 2047;
        const int NP = NMID * DK;
        float s = Opart[e] + Opart[e + NP] + Opart[e + 2 * NP] + Opart[e + 3 * NP];
        out[((size_t)b * L_ + S_ + q) * DK + c] = s;
    } else {
        const int e2 = e - NMID * DK;
        const int er = e2 >> 6, c = e2 & 63;
        const int b  = er >> 8, r = er & 255;
        const int gQ = (r < 128) ? r : (2048 + r);
        const int NP = NEDGE * DK;
        float s = Oe[e2] + Oe[e2 + NP] + Oe[e2 + 2 * NP] + Oe[e2 + 3 * NP];
        out[((size_t)b * L_ + gQ) * DK + c] = s;
    }
}

// ---------------------------------------------------------------------------
extern "C" void kernel_launch(void* const* d_in, const int* in_sizes, int n_in,
                              void* d_out, int out_size, void* d_ws, size_t ws_size,
                              hipStream_t stream)
{
    const float* x    = (const float*)d_in[0];
    const float* Wq   = (const float*)d_in[1];
    const float* Wk   = (const float*)d_in[2];
    const float* Wv   = (const float*)d_in[3];
    const float* Wqs  = (const float*)d_in[4];
    const float* Wks  = (const float*)d_in[5];
    const float* Wvs  = (const float*)d_in[6];
    const float* Wqe  = (const float*)d_in[7];
    const float* Wke  = (const float*)d_in[8];
    const float* Wve  = (const float*)d_in[9];
    const float* g0   = (const float*)d_in[10];
    const float* b0   = (const float*)d_in[11];
    const float* gs   = (const float*)d_in[12];
    const float* bs   = (const float*)d_in[13];
    const float* ge   = (const float*)d_in[14];
    const float* be   = (const float*)d_in[15];
    const float* cope = (const float*)d_in[16];

    const size_t NR = (size_t)B_ * L_;               // 9216 rows
    f16*   qsp   = (f16*)d_ws;                       // NR*128 h (hi|lo)
    f16*   ksp   = qsp + NR * 128;                   // NR*128 h
    f16*   vhT   = ksp + NR * 128;                   // NR*64 h (4 batches x 64 dims x L)
    float* G     = (float*)(vhT + NR * 64);          // NMID*32 f32
    float* Opart = G + (size_t)NMID * 32;            // 4*NMID*64 f32
    float* Oe    = Opart + (size_t)4 * NMID * DK;    // 4*NEDGE*64 f32
    float* D     = Oe + (size_t)4 * NEDGE * DK;      // NMID*NCOLS f32
    float* De    = D + (size_t)NMID * NCOLS;         // NEDGE*LE f32
    float* out   = (float*)d_out;

    k_proj<<<dim3(144, 3), 256, 0, stream>>>(x, Wq, Wk, Wv, Wqs, Wks, Wvs,
                                             Wqe, Wke, Wve, g0, b0, gs, bs,
                                             ge, be, qsp, ksp, vhT);
    k_dots<<<dim3(72, 36), 256, 0, stream>>>(qsp, ksp, D, G, De);
    k_scan<<<NMID + NEDGE, 256, 0, stream>>>(qsp, cope, G, D, De);
    k_pv  <<<dim3(144, 4), 256, 0, stream>>>((const f16*)D, (const f16*)De,
                                             vhT, Opart, Oe);
    k_merge<<<(NMID + NEDGE) * DK / 256, 256, 0, stream>>>(Opart, Oe, out);
}

// Round 12
// 199.229 us; speedup vs baseline: 1.2983x; 1.0124x over previous
//
#include <hip/hip_runtime.h>
#include <math.h>

#define B_    4
#define SEQ_  2048
#define S_    128
#define L_    2304          // SEQ + 2*S
#define DIN   512
#define DK    64
#define NEGINF (-1e30f)
#define SCALE 0.125f
#define NCOLS 2176          // start(128) + mid(2048) key columns in D (fp16)
#define NMID  8192          // B_*SEQ_
#define NEDGE 1024          // B_*2*S_
#define LE    2304          // edge De row length (fp16)

typedef _Float16 f16;
typedef __attribute__((ext_vector_type(8))) _Float16 half8;
typedef __attribute__((ext_vector_type(4))) float f32x4;

union U4 { uint4 u; f16 h[8]; };

// ---------------------------------------------------------------------------
// k_proj: fused LayerNorm + QKV via split-fp16 MFMA (3 terms q,k; 1 term v).
// grid (144, 3) x 256. Emits split-fp16 q/k and transposed fp16 V.
// ---------------------------------------------------------------------------
__global__ __launch_bounds__(256) void k_proj(
    const float* __restrict__ x,
    const float* __restrict__ Wq,  const float* __restrict__ Wk,  const float* __restrict__ Wv,
    const float* __restrict__ Wqs, const float* __restrict__ Wks, const float* __restrict__ Wvs,
    const float* __restrict__ Wqe, const float* __restrict__ Wke, const float* __restrict__ Wve,
    const float* __restrict__ g0, const float* __restrict__ b0,
    const float* __restrict__ gs, const float* __restrict__ bs,
    const float* __restrict__ ge, const float* __restrict__ be,
    f16* __restrict__ qsp, f16* __restrict__ ksp, f16* __restrict__ vhT)
{
    __shared__ f16 As[64 * 136];   // [row][hi 0..63 | lo 64..127 | pad]
    __shared__ f16 Bs[64 * 136];
    __shared__ float mean_s[64], rstd_s[64];
    const int tid  = threadIdx.x;
    const int row0 = blockIdx.x * 64;
    const int rseq = row0 % L_;
    const int seg  = (rseq < S_) ? 0 : (rseq >= L_ - S_) ? 2 : 1;
    const int m    = blockIdx.y;
    const float* W;
    if (m == 0)      W = (seg == 0) ? Wqs : (seg == 2) ? Wqe : Wq;
    else if (m == 1) W = (seg == 0) ? Wks : (seg == 2) ? Wke : Wk;
    else             W = (seg == 0) ? Wvs : (seg == 2) ? Wve : Wv;
    const float* gg = (seg == 0) ? gs : (seg == 2) ? ge : g0;
    const float* bb = (seg == 0) ? bs : (seg == 2) ? be : b0;

    // row stats: 4 threads per row, 128 elems each
    {
        const int rr = tid >> 2, qq = tid & 3;
        const float4* xr = (const float4*)(x + (size_t)(row0 + rr) * DIN) + qq * 32;
        float s = 0.f, s2 = 0.f;
        #pragma unroll
        for (int i = 0; i < 32; ++i) {
            float4 v = xr[i];
            s  += v.x + v.y + v.z + v.w;
            s2 += v.x * v.x + v.y * v.y + v.z * v.z + v.w * v.w;
        }
        s  += __shfl_xor(s, 1);  s  += __shfl_xor(s, 2);
        s2 += __shfl_xor(s2, 1); s2 += __shfl_xor(s2, 2);
        if (qq == 0) {
            float mean = s * (1.f / DIN);
            mean_s[rr] = mean;
            rstd_s[rr] = rsqrtf(s2 * (1.f / DIN) - mean * mean + 1e-5f);
        }
    }

    const int w = tid >> 6, lane = tid & 63;
    const int cl = lane & 15, quad = lane >> 4;
    const int r0 = 32 * (w >> 1), c0 = 32 * (w & 1);

    f32x4 acc[2][2];
    #pragma unroll
    for (int i = 0; i < 2; ++i)
        #pragma unroll
        for (int j = 0; j < 2; ++j) acc[i][j] = 0.f;

    for (int kc = 0; kc < DIN; kc += 64) {
        __syncthreads();
        #pragma unroll
        for (int i = 0; i < 2; ++i) {
            int g = tid + 256 * i;           // (row, 8-col group)
            int r = g >> 3, c8 = g & 7;
            const float* xp = x + (size_t)(row0 + r) * DIN + kc + c8 * 8;
            float4 a0 = *(const float4*)xp;
            float4 a1 = *(const float4*)(xp + 4);
            float4 gA = *(const float4*)(gg + kc + c8 * 8);
            float4 gB = *(const float4*)(gg + kc + c8 * 8 + 4);
            float4 bA = *(const float4*)(bb + kc + c8 * 8);
            float4 bB = *(const float4*)(bb + kc + c8 * 8 + 4);
            float mean = mean_s[r], rstd = rstd_s[r];
            float n[8];
            n[0] = (a0.x - mean) * rstd * gA.x + bA.x;
            n[1] = (a0.y - mean) * rstd * gA.y + bA.y;
            n[2] = (a0.z - mean) * rstd * gA.z + bA.z;
            n[3] = (a0.w - mean) * rstd * gA.w + bA.w;
            n[4] = (a1.x - mean) * rstd * gB.x + bB.x;
            n[5] = (a1.y - mean) * rstd * gB.y + bB.y;
            n[6] = (a1.z - mean) * rstd * gB.z + bB.z;
            n[7] = (a1.w - mean) * rstd * gB.w + bB.w;
            U4 hi, lo;
            #pragma unroll
            for (int j = 0; j < 8; ++j) {
                hi.h[j] = (f16)n[j];
                lo.h[j] = (f16)(n[j] - (float)hi.h[j]);
            }
            *(uint4*)(As + r * 136 + c8 * 8)      = hi.u;
            *(uint4*)(As + r * 136 + 64 + c8 * 8) = lo.u;
        }
        #pragma unroll
        for (int i = 0; i < 4; ++i) {
            int g = tid + 256 * i;
            int k = g >> 4, c4 = g & 15;
            float4 wv = ((const float4*)W)[(size_t)(kc + k) * 16 + c4];
            f16 h0 = (f16)wv.x, h1 = (f16)wv.y, h2 = (f16)wv.z, h3 = (f16)wv.w;
            Bs[(c4 * 4 + 0) * 136 + k] = h0;
            Bs[(c4 * 4 + 1) * 136 + k] = h1;
            Bs[(c4 * 4 + 2) * 136 + k] = h2;
            Bs[(c4 * 4 + 3) * 136 + k] = h3;
            Bs[(c4 * 4 + 0) * 136 + 64 + k] = (f16)(wv.x - (float)h0);
            Bs[(c4 * 4 + 1) * 136 + 64 + k] = (f16)(wv.y - (float)h1);
            Bs[(c4 * 4 + 2) * 136 + 64 + k] = (f16)(wv.z - (float)h2);
            Bs[(c4 * 4 + 3) * 136 + 64 + k] = (f16)(wv.w - (float)h3);
        }
        __syncthreads();
        #pragma unroll
        for (int h = 0; h < 2; ++h) {
            half8 ah[2], al[2], bh[2], bl[2];
            #pragma unroll
            for (int rs = 0; rs < 2; ++rs) {
                const f16* base = As + (r0 + 16 * rs + cl) * 136 + h * 32 + quad * 8;
                ah[rs] = *(const half8*)(base);
                al[rs] = *(const half8*)(base + 64);
            }
            #pragma unroll
            for (int cs = 0; cs < 2; ++cs) {
                const f16* base = Bs + (c0 + 16 * cs + cl) * 136 + h * 32 + quad * 8;
                bh[cs] = *(const half8*)(base);
                bl[cs] = *(const half8*)(base + 64);
            }
            #pragma unroll
            for (int rs = 0; rs < 2; ++rs)
                #pragma unroll
                for (int cs = 0; cs < 2; ++cs) {
                    acc[rs][cs] = __builtin_amdgcn_mfma_f32_16x16x32_f16(ah[rs], bh[cs], acc[rs][cs], 0, 0, 0);
                    if (m < 2) {
                        acc[rs][cs] = __builtin_amdgcn_mfma_f32_16x16x32_f16(ah[rs], bl[cs], acc[rs][cs], 0, 0, 0);
                        acc[rs][cs] = __builtin_amdgcn_mfma_f32_16x16x32_f16(al[rs], bh[cs], acc[rs][cs], 0, 0, 0);
                    }
                }
        }
    }

    const int bI = row0 / L_;
    const int rb = row0 - bI * L_;
    f16* sp = (m == 0) ? qsp : ksp;
    #pragma unroll
    for (int rs = 0; rs < 2; ++rs)
        #pragma unroll
        for (int cs = 0; cs < 2; ++cs)
            #pragma unroll
            for (int r = 0; r < 4; ++r) {
                int lrow = r0 + 16 * rs + quad * 4 + r;
                int col  = c0 + 16 * cs + cl;
                float v  = acc[rs][cs][r];
                size_t grow = (size_t)(row0 + lrow);
                if (m < 2) {
                    f16 hv = (f16)v;
                    sp[grow * 128 + col]      = hv;
                    sp[grow * 128 + 64 + col] = (f16)(v - (float)hv);
                } else {
                    vhT[(size_t)(bI * 64 + col) * L_ + rb + lrow] = (f16)v;
                }
            }
}

// ---------------------------------------------------------------------------
// k_dots: mid + edge dots via split-fp16 MFMA; fp16 D/De; exact fp32 G sums.
// grid (72, 36) x 256. bx<64: mid. bx>=64: edge.
// ---------------------------------------------------------------------------
__global__ __launch_bounds__(256) void k_dots(
    const f16* __restrict__ qsp, const f16* __restrict__ ksp,
    f16* __restrict__ D, float* __restrict__ G, f16* __restrict__ De)
{
    const int bx = blockIdx.x, by = blockIdx.y;
    const bool edge = (bx >= 64);
    int b, q0 = 0;
    size_t qrow0;
    if (!edge) {
        if (by >= 34) return;
        b = bx >> 4;
        q0 = (bx * 128) & 2047;
        qrow0 = (size_t)b * L_ + S_ + q0;
    } else {
        int ex = bx - 64;
        b = ex >> 1;
        int half = ex & 1;
        if (half == 0 && by > 1) return;      // start rows see only cols <128
        qrow0 = (size_t)b * L_ + (half ? 2176 : 0);
    }
    const int col0 = by * 64;
    const size_t krow0 = (size_t)b * L_ + col0;

    __shared__ f16 Qs[128 * 136];
    __shared__ f16 Ks[64 * 136];
    const int tid = threadIdx.x;

    #pragma unroll
    for (int i = 0; i < 8; ++i) {
        int g = tid + 256 * i;
        int r = g >> 4, c = g & 15;
        *(uint4*)(Qs + r * 136 + c * 8) = *(const uint4*)(qsp + (qrow0 + r) * 128 + c * 8);
    }
    #pragma unroll
    for (int i = 0; i < 4; ++i) {
        int g = tid + 256 * i;
        int r = g >> 4, c = g & 15;
        *(uint4*)(Ks + r * 136 + c * 8) = *(const uint4*)(ksp + (krow0 + r) * 128 + c * 8);
    }
    __syncthreads();

    const int w = tid >> 6, lane = tid & 63;
    const int cl = lane & 15, quad = lane >> 4;

    f32x4 acc[2][4];
    #pragma unroll
    for (int i = 0; i < 2; ++i)
        #pragma unroll
        for (int j = 0; j < 4; ++j) acc[i][j] = 0.f;

    #pragma unroll
    for (int h = 0; h < 2; ++h) {
        half8 ah[2], al[2], bh[4], bl[4];
        #pragma unroll
        for (int rs = 0; rs < 2; ++rs) {
            const f16* base = Qs + (32 * w + 16 * rs + cl) * 136 + h * 32 + quad * 8;
            ah[rs] = *(const half8*)(base);
            al[rs] = *(const half8*)(base + 64);
        }
        #pragma unroll
        for (int c = 0; c < 4; ++c) {
            const f16* base = Ks + (16 * c + cl) * 136 + h * 32 + quad * 8;
            bh[c] = *(const half8*)(base);
            bl[c] = *(const half8*)(base + 64);
        }
        #pragma unroll
        for (int rs = 0; rs < 2; ++rs)
            #pragma unroll
            for (int c = 0; c < 4; ++c) {
                acc[rs][c] = __builtin_amdgcn_mfma_f32_16x16x32_f16(ah[rs], bh[c], acc[rs][c], 0, 0, 0);
                acc[rs][c] = __builtin_amdgcn_mfma_f32_16x16x32_f16(ah[rs], bl[c], acc[rs][c], 0, 0, 0);
                acc[rs][c] = __builtin_amdgcn_mfma_f32_16x16x32_f16(al[rs], bh[c], acc[rs][c], 0, 0, 0);
            }
    }

    if (!edge) {
        const int gr0 = bx * 128;
        const bool writeD = (by < 2) || ((by - 2) <= (q0 >> 6) + 1);
        if (writeD) {
            #pragma unroll
            for (int rs = 0; rs < 2; ++rs)
                #pragma unroll
                for (int c = 0; c < 4; ++c)
                    #pragma unroll
                    for (int r = 0; r < 4; ++r) {
                        int mrow = gr0 + 32 * w + 16 * rs + quad * 4 + r;
                        int n    = col0 + 16 * c + cl;
                        D[(size_t)mrow * NCOLS + n] = (f16)acc[rs][c][r];
                    }
        }
        if (by >= 2) {
            const int chm = by - 2;
            #pragma unroll
            for (int rs = 0; rs < 2; ++rs)
                #pragma unroll
                for (int r = 0; r < 4; ++r) {
                    float s = 0.f;
                    #pragma unroll
                    for (int c = 0; c < 4; ++c)
                        s += 1.f / (1.f + __expf(-acc[rs][c][r]));
                    #pragma unroll
                    for (int off = 1; off < 16; off <<= 1) s += __shfl_xor(s, off);
                    if (cl == 0)
                        G[(size_t)(gr0 + 32 * w + 16 * rs + quad * 4 + r) * 32 + chm] = s;
                }
        }
    } else {
        const int er0 = (bx - 64) * 128;
        #pragma unroll
        for (int rs = 0; rs < 2; ++rs)
            #pragma unroll
            for (int c = 0; c < 4; ++c)
                #pragma unroll
                for (int r = 0; r < 4; ++r) {
                    int erow = er0 + 32 * w + 16 * rs + quad * 4 + r;
                    int n    = col0 + 16 * c + cl;
                    De[(size_t)erow * LE + n] = (f16)acc[rs][c][r];
                }
    }
}

// ---------------------------------------------------------------------------
// k_scan: grid 9216 x 256.
// gr<8192: mid row — cope li + fp16 gates (intra-chunk) + EXACT G suffix
//          table (inter-chunk) -> CoPE bias -> softmax -> fp16 P in place.
// gr>=8192: edge row causal softmax -> fp16 Pe in place.
// ---------------------------------------------------------------------------
__global__ __launch_bounds__(256) void k_scan(
    const f16* __restrict__ qsp, const float* __restrict__ cope,
    const float* __restrict__ G, f16* __restrict__ D, f16* __restrict__ De)
{
    __shared__ f16   qvh[128];
    __shared__ float li[128];
    __shared__ float Gs[32];
    __shared__ float Gsf[32];          // Gsf[c] = sum_{c' > c} Gs[c']
    __shared__ float wmax[4], wsum[4];
    const int tid = threadIdx.x;
    const int gr  = blockIdx.x;
    const int lane = tid & 63, wid = tid >> 6;

    if (gr < NMID) {
        const int b = gr >> 11;
        const int q = gr & 2047;
        const size_t grow = (size_t)b * L_ + S_ + q;
        const int qlim = (q & ~63) + 64;

        if (tid < 16) ((uint4*)qvh)[tid] = ((const uint4*)(qsp + grow * 128))[tid];
        if (tid >= 16 && tid < 24)
            ((float4*)Gs)[tid - 16] = ((const float4*)G)[(size_t)gr * 8 + tid - 16];
        __syncthreads();
        if (tid < 128) {
            float a = 0.f;
            #pragma unroll
            for (int d = 0; d < DK; ++d)
                a += ((float)qvh[d] + (float)qvh[64 + d]) * cope[d * S_ + tid];
            li[tid] = a;
        }
        if (tid >= 128 && tid < 160) {
            int c = tid - 128;
            float s = 0.f;
            for (int cc = c + 1; cc < 32; ++cc) s += Gs[cc];
            Gsf[c] = s;
        }

        f16* Dr = D + (size_t)gr * NCOLS;
        const int j0 = tid * 8;
        const int cg = tid >> 3, sl = tid & 7;   // 64-key chunk, 8-lane segment
        float dot[8], gte[8];
        float csum = 0.f;
        if (j0 < qlim) {
            U4 t; t.u = *(const uint4*)(Dr + 128 + j0);
            #pragma unroll
            for (int jj = 0; jj < 8; ++jj) {
                dot[jj] = (float)t.h[jj];
                gte[jj] = 1.f / (1.f + __expf(-dot[jj]));
                csum += gte[jj];
            }
        } else {
            #pragma unroll
            for (int jj = 0; jj < 8; ++jj) { dot[jj] = 0.f; gte[jj] = 0.f; }
        }
        float sv = (tid < 128) ? (float)Dr[tid] * SCALE : NEGINF;

        // intra-chunk inclusive suffix over the 8-thread segment
        float inc = csum;
        #pragma unroll
        for (int off = 1; off < 8; off <<= 1) {
            float u = __shfl_down(inc, off, 8);
            if (sl + off < 8) inc += u;
        }
        __syncthreads();                  // publish li, Gsf
        float run = (inc - csum) + Gsf[cg];   // exclusive suffix, exact tail

        float p8[8];
        #pragma unroll
        for (int jj = 7; jj >= 0; --jj) {
            run += gte[jj];
            float pos = fminf(run, (float)(S_ - 1));
            float pfl = floorf(pos);
            int ic  = (int)ceilf(pos);
            int ifl = (int)pfl;
            float w = pos - pfl;
            float bias = li[ic] * w + li[ifl] * (1.f - w);
            p8[jj] = (j0 + jj <= q) ? dot[jj] * SCALE + bias : NEGINF;
        }

        float mx = sv;
        #pragma unroll
        for (int jj = 0; jj < 8; ++jj) mx = fmaxf(mx, p8[jj]);
        #pragma unroll
        for (int off = 1; off < 64; off <<= 1) mx = fmaxf(mx, __shfl_xor(mx, off));
        if (lane == 0) wmax[wid] = mx;
        __syncthreads();
        mx = fmaxf(fmaxf(wmax[0], wmax[1]), fmaxf(wmax[2], wmax[3]));

        float lsum = 0.f;
        float e8[8];
        #pragma unroll
        for (int jj = 0; jj < 8; ++jj) {
            e8[jj] = __expf(p8[jj] - mx);
            lsum += e8[jj];
        }
        float es = 0.f;
        if (tid < 128) { es = __expf(sv - mx); lsum += es; }
        #pragma unroll
        for (int off = 1; off < 64; off <<= 1) lsum += __shfl_xor(lsum, off);
        if (lane == 0) wsum[wid] = lsum;
        __syncthreads();
        float inv = 1.f / (wsum[0] + wsum[1] + wsum[2] + wsum[3]);

        if (j0 < qlim) {
            U4 o;
            #pragma unroll
            for (int jj = 0; jj < 8; ++jj) o.h[jj] = (f16)(e8[jj] * inv);
            *(uint4*)(Dr + 128 + j0) = o.u;
        }
        if (tid < 128) Dr[tid] = (f16)(es * inv);
    } else {
        const int er = gr - NMID;
        const int r  = er & 255;
        const int Q  = (r < 128) ? r : (2048 + r);
        f16* Er = De + (size_t)er * LE;

        float v[9];
        #pragma unroll
        for (int i = 0; i < 9; ++i) {
            int j = tid + 256 * i;
            float d = (float)Er[j];
            v[i] = (j <= Q) ? d * SCALE : NEGINF;
        }
        float mx = v[0];
        #pragma unroll
        for (int i = 1; i < 9; ++i) mx = fmaxf(mx, v[i]);
        #pragma unroll
        for (int off = 1; off < 64; off <<= 1) mx = fmaxf(mx, __shfl_xor(mx, off));
        if (lane == 0) wmax[wid] = mx;
        __syncthreads();
        mx = fmaxf(fmaxf(wmax[0], wmax[1]), fmaxf(wmax[2], wmax[3]));

        float lsum = 0.f;
        #pragma unroll
        for (int i = 0; i < 9; ++i) {
            v[i] = __expf(v[i] - mx);
            lsum += v[i];
        }
        #pragma unroll
        for (int off = 1; off < 64; off <<= 1) lsum += __shfl_xor(lsum, off);
        if (lane == 0) wsum[wid] = lsum;
        __syncthreads();
        float inv = 1.f / (wsum[0] + wsum[1] + wsum[2] + wsum[3]);

        #pragma unroll
        for (int i = 0; i < 9; ++i)
            Er[tid + 256 * i] = (f16)(v[i] * inv);
    }
}

// ---------------------------------------------------------------------------
// k_pv: mid + edge PV via fp16 MFMA, 4-way K-split, atomicAdd into out.
// grid (144, 4) x 256. bx<128: mid. bx>=128: edge. out must be zeroed.
// ---------------------------------------------------------------------------
__global__ __launch_bounds__(256) void k_pv(
    const f16* __restrict__ Pmid, const f16* __restrict__ Pedge,
    const f16* __restrict__ vhT, float* __restrict__ out)
{
    __shared__ f16 Ps[64 * 72];
    __shared__ f16 Vt[64 * 72];
    const int tid = threadIdx.x;
    const int bx  = blockIdx.x;
    const int ks  = blockIdx.y;
    const bool edge = (bx >= 128);

    const f16* Pb;
    size_t pitch;
    int row0, b, cap, cmax;
    if (!edge) {
        row0 = bx * 64;
        b = row0 >> 11;
        int q0 = row0 & 2047;
        Pb = Pmid; pitch = NCOLS; cap = 34;
        cmax = (191 + q0) >> 6;
    } else {
        row0 = (bx - 128) * 64;
        b = row0 >> 8;
        int r0 = row0 & 255;
        Pb = Pedge; pitch = LE; cap = 36;
        int Qmax = (r0 < 128) ? (r0 + 63) : (2048 + r0 + 63);
        cmax = Qmax >> 6;
    }
    const int c_beg = ks * 9;
    int c_end = c_beg + 9;
    if (c_end > cap) c_end = cap;
    if (c_end > cmax + 1) c_end = cmax + 1;
    if (c_end <= c_beg) return;

    const int w = tid >> 6, lane = tid & 63;
    const int cl = lane & 15, quad = lane >> 4;
    f32x4 acc[4];
    #pragma unroll
    for (int c = 0; c < 4; ++c) acc[c] = 0.f;

    for (int ch = c_beg; ch < c_end; ++ch) {
        __syncthreads();
        #pragma unroll
        for (int i = 0; i < 2; ++i) {
            int g = tid + 256 * i;
            int r = g >> 3, c = g & 7;
            *(uint4*)(Ps + r * 72 + c * 8) =
                *(const uint4*)(Pb + (size_t)(row0 + r) * pitch + ch * 64 + c * 8);
            *(uint4*)(Vt + r * 72 + c * 8) =
                *(const uint4*)(vhT + (size_t)(b * 64 + r) * L_ + ch * 64 + c * 8);
        }
        __syncthreads();
        #pragma unroll
        for (int h = 0; h < 2; ++h) {
            half8 a = *(const half8*)(Ps + (16 * w + cl) * 72 + h * 32 + quad * 8);
            #pragma unroll
            for (int c = 0; c < 4; ++c) {
                half8 bv = *(const half8*)(Vt + (16 * c + cl) * 72 + h * 32 + quad * 8);
                acc[c] = __builtin_amdgcn_mfma_f32_16x16x32_f16(a, bv, acc[c], 0, 0, 0);
            }
        }
    }
    #pragma unroll
    for (int c = 0; c < 4; ++c)
        #pragma unroll
        for (int r = 0; r < 4; ++r) {
            int lrow = row0 + 16 * w + quad * 4 + r;
            int n    = 16 * c + cl;
            size_t orow;
            if (!edge) {
                orow = (size_t)b * L_ + S_ + (lrow & 2047);
            } else {
                int rr = lrow & 255;
                int gQ = (rr < 128) ? rr : (2048 + rr);
                orow = (size_t)b * L_ + gQ;
            }
            atomicAdd(&out[orow * DK + n], acc[c][r]);
        }
}

// ---------------------------------------------------------------------------
extern "C" void kernel_launch(void* const* d_in, const int* in_sizes, int n_in,
                              void* d_out, int out_size, void* d_ws, size_t ws_size,
                              hipStream_t stream)
{
    const float* x    = (const float*)d_in[0];
    const float* Wq   = (const float*)d_in[1];
    const float* Wk   = (const float*)d_in[2];
    const float* Wv   = (const float*)d_in[3];
    const float* Wqs  = (const float*)d_in[4];
    const float* Wks  = (const float*)d_in[5];
    const float* Wvs  = (const float*)d_in[6];
    const float* Wqe  = (const float*)d_in[7];
    const float* Wke  = (const float*)d_in[8];
    const float* Wve  = (const float*)d_in[9];
    const float* g0   = (const float*)d_in[10];
    const float* b0   = (const float*)d_in[11];
    const float* gs   = (const float*)d_in[12];
    const float* bs   = (const float*)d_in[13];
    const float* ge   = (const float*)d_in[14];
    const float* be   = (const float*)d_in[15];
    const float* cope = (const float*)d_in[16];

    const size_t NR = (size_t)B_ * L_;               // 9216 rows
    f16*   qsp = (f16*)d_ws;                         // NR*128 h (hi|lo)
    f16*   ksp = qsp + NR * 128;                     // NR*128 h
    f16*   vhT = ksp + NR * 128;                     // NR*64 h
    float* G   = (float*)(vhT + NR * 64);            // NMID*32 f32
    f16*   D   = (f16*)(G + (size_t)NMID * 32);      // NMID*NCOLS h
    f16*   De  = D + (size_t)NMID * NCOLS;           // NEDGE*LE h
    float* out = (float*)d_out;

    hipMemsetAsync(out, 0, (size_t)out_size * sizeof(float), stream);
    k_proj<<<dim3(144, 3), 256, 0, stream>>>(x, Wq, Wk, Wv, Wqs, Wks, Wvs,
                                             Wqe, Wke, Wve, g0, b0, gs, bs,
                                             ge, be, qsp, ksp, vhT);
    k_dots<<<dim3(72, 36), 256, 0, stream>>>(qsp, ksp, D, G, De);
    k_scan<<<NMID + NEDGE, 256, 0, stream>>>(qsp, cope, G, D, De);
    k_pv  <<<dim3(144, 4), 256, 0, stream>>>(D, De, vhT, out);
}

// Round 13
// 192.490 us; speedup vs baseline: 1.3438x; 1.0350x over previous
//
#include <hip/hip_runtime.h>
#include <math.h>

#define B_    4
#define SEQ_  2048
#define S_    128
#define L_    2304          // SEQ + 2*S
#define DIN   512
#define DK    64
#define NEGINF (-1e30f)
#define SCALE 0.125f
#define NCOLS 2176          // start(128) + mid(2048) key columns in D (fp16)
#define NMID  8192          // B_*SEQ_
#define NEDGE 1024          // B_*2*S_
#define LE    2304          // edge De row length (fp16)

typedef _Float16 f16;
typedef __attribute__((ext_vector_type(8))) _Float16 half8;
typedef __attribute__((ext_vector_type(4))) float f32x4;

union U4 { uint4 u; f16 h[8]; };

// ---------------------------------------------------------------------------
// k_wsplit: pre-split all 9 W matrices (512x64 f32) into fp16 hi/lo,
// transposed layout Wsp[mat][col][k: hi 0..511 | lo 512..1023].
// grid (8, 9) x 256: 64-k tile per block.
// ---------------------------------------------------------------------------
__global__ __launch_bounds__(256) void k_wsplit(
    const float* __restrict__ Wq,  const float* __restrict__ Wk,  const float* __restrict__ Wv,
    const float* __restrict__ Wqs, const float* __restrict__ Wks, const float* __restrict__ Wvs,
    const float* __restrict__ Wqe, const float* __restrict__ Wke, const float* __restrict__ Wve,
    f16* __restrict__ Wsp)
{
    __shared__ float xs[64 * 68];
    const int kt  = blockIdx.x;         // k tile 0..7
    const int mat = blockIdx.y;         // 0..8
    const float* W;
    switch (mat) {
        case 0: W = Wq;  break; case 1: W = Wk;  break; case 2: W = Wv;  break;
        case 3: W = Wqs; break; case 4: W = Wks; break; case 5: W = Wvs; break;
        case 6: W = Wqe; break; case 7: W = Wke; break; default: W = Wve; break;
    }
    const int tid = threadIdx.x;
    const int k0  = kt * 64;
    #pragma unroll
    for (int i = 0; i < 4; ++i) {
        int g = tid + 256 * i;          // 64 k x 16 float4
        int k = g >> 4, c4 = g & 15;
        *(float4*)(xs + k * 68 + c4 * 4) = ((const float4*)W)[(size_t)(k0 + k) * 16 + c4];
    }
    __syncthreads();
    const int col = tid & 63, hf = tid >> 6;
    const int kk0 = hf * 16;
    U4 hi0, hi1, lo0, lo1;
    #pragma unroll
    for (int j = 0; j < 8; ++j) {
        float v0 = xs[(kk0 + j) * 68 + col];
        float v1 = xs[(kk0 + 8 + j) * 68 + col];
        hi0.h[j] = (f16)v0; lo0.h[j] = (f16)(v0 - (float)hi0.h[j]);
        hi1.h[j] = (f16)v1; lo1.h[j] = (f16)(v1 - (float)hi1.h[j]);
    }
    f16* dst = Wsp + (size_t)mat * 65536 + (size_t)col * 1024 + k0 + kk0;
    *(uint4*)(dst)       = hi0.u;
    *(uint4*)(dst + 8)   = hi1.u;
    *(uint4*)(dst + 512) = lo0.u;
    *(uint4*)(dst + 520) = lo1.u;
}

// ---------------------------------------------------------------------------
// k_proj: fused LayerNorm + QKV via split-fp16 MFMA (3 terms q,k; 1 term v).
// grid (144, 3) x 256. Bs staged from pre-split Wsp (uint4 copies).
// ---------------------------------------------------------------------------
__global__ __launch_bounds__(256) void k_proj(
    const float* __restrict__ x, const f16* __restrict__ Wsp,
    const float* __restrict__ g0, const float* __restrict__ b0,
    const float* __restrict__ gs, const float* __restrict__ bs,
    const float* __restrict__ ge, const float* __restrict__ be,
    f16* __restrict__ qsp, f16* __restrict__ ksp, f16* __restrict__ vhT)
{
    __shared__ f16 As[64 * 136];   // [row][hi 0..63 | lo 64..127 | pad]
    __shared__ f16 Bs[64 * 136];
    __shared__ float mean_s[64], rstd_s[64];
    const int tid  = threadIdx.x;
    const int row0 = blockIdx.x * 64;
    const int rseq = row0 % L_;
    const int seg  = (rseq < S_) ? 0 : (rseq >= L_ - S_) ? 2 : 1;
    const int m    = blockIdx.y;
    const int mat  = m + ((seg == 0) ? 3 : (seg == 2) ? 6 : 0);
    const f16* Wc  = Wsp + (size_t)mat * 65536;
    const float* gg = (seg == 0) ? gs : (seg == 2) ? ge : g0;
    const float* bb = (seg == 0) ? bs : (seg == 2) ? be : b0;

    // row stats: 4 threads per row, 128 elems each
    {
        const int rr = tid >> 2, qq = tid & 3;
        const float4* xr = (const float4*)(x + (size_t)(row0 + rr) * DIN) + qq * 32;
        float s = 0.f, s2 = 0.f;
        #pragma unroll
        for (int i = 0; i < 32; ++i) {
            float4 v = xr[i];
            s  += v.x + v.y + v.z + v.w;
            s2 += v.x * v.x + v.y * v.y + v.z * v.z + v.w * v.w;
        }
        s  += __shfl_xor(s, 1);  s  += __shfl_xor(s, 2);
        s2 += __shfl_xor(s2, 1); s2 += __shfl_xor(s2, 2);
        if (qq == 0) {
            float mean = s * (1.f / DIN);
            mean_s[rr] = mean;
            rstd_s[rr] = rsqrtf(s2 * (1.f / DIN) - mean * mean + 1e-5f);
        }
    }

    const int w = tid >> 6, lane = tid & 63;
    const int cl = lane & 15, quad = lane >> 4;
    const int r0 = 32 * (w >> 1), c0 = 32 * (w & 1);

    f32x4 acc[2][2];
    #pragma unroll
    for (int i = 0; i < 2; ++i)
        #pragma unroll
        for (int j = 0; j < 2; ++j) acc[i][j] = 0.f;

    for (int kc = 0; kc < DIN; kc += 64) {
        __syncthreads();
        #pragma unroll
        for (int i = 0; i < 2; ++i) {
            int g = tid + 256 * i;           // (row, 8-col group)
            int r = g >> 3, c8 = g & 7;
            const float* xp = x + (size_t)(row0 + r) * DIN + kc + c8 * 8;
            float4 a0 = *(const float4*)xp;
            float4 a1 = *(const float4*)(xp + 4);
            float4 gA = *(const float4*)(gg + kc + c8 * 8);
            float4 gB = *(const float4*)(gg + kc + c8 * 8 + 4);
            float4 bA = *(const float4*)(bb + kc + c8 * 8);
            float4 bB = *(const float4*)(bb + kc + c8 * 8 + 4);
            float mean = mean_s[r], rstd = rstd_s[r];
            float n[8];
            n[0] = (a0.x - mean) * rstd * gA.x + bA.x;
            n[1] = (a0.y - mean) * rstd * gA.y + bA.y;
            n[2] = (a0.z - mean) * rstd * gA.z + bA.z;
            n[3] = (a0.w - mean) * rstd * gA.w + bA.w;
            n[4] = (a1.x - mean) * rstd * gB.x + bB.x;
            n[5] = (a1.y - mean) * rstd * gB.y + bB.y;
            n[6] = (a1.z - mean) * rstd * gB.z + bB.z;
            n[7] = (a1.w - mean) * rstd * gB.w + bB.w;
            U4 hi, lo;
            #pragma unroll
            for (int j = 0; j < 8; ++j) {
                hi.h[j] = (f16)n[j];
                lo.h[j] = (f16)(n[j] - (float)hi.h[j]);
            }
            *(uint4*)(As + r * 136 + c8 * 8)      = hi.u;
            *(uint4*)(As + r * 136 + 64 + c8 * 8) = lo.u;
        }
        #pragma unroll
        for (int i = 0; i < 2; ++i) {
            int g = tid + 256 * i;           // 64 cols x 8 groups
            int col = g >> 3, c8 = g & 7;
            const f16* src = Wc + (size_t)col * 1024 + kc + c8 * 8;
            *(uint4*)(Bs + col * 136 + c8 * 8)      = *(const uint4*)(src);
            *(uint4*)(Bs + col * 136 + 64 + c8 * 8) = *(const uint4*)(src + 512);
        }
        __syncthreads();
        #pragma unroll
        for (int h = 0; h < 2; ++h) {
            half8 ah[2], al[2], bh[2], bl[2];
            #pragma unroll
            for (int rs = 0; rs < 2; ++rs) {
                const f16* base = As + (r0 + 16 * rs + cl) * 136 + h * 32 + quad * 8;
                ah[rs] = *(const half8*)(base);
                al[rs] = *(const half8*)(base + 64);
            }
            #pragma unroll
            for (int cs = 0; cs < 2; ++cs) {
                const f16* base = Bs + (c0 + 16 * cs + cl) * 136 + h * 32 + quad * 8;
                bh[cs] = *(const half8*)(base);
                bl[cs] = *(const half8*)(base + 64);
            }
            #pragma unroll
            for (int rs = 0; rs < 2; ++rs)
                #pragma unroll
                for (int cs = 0; cs < 2; ++cs) {
                    acc[rs][cs] = __builtin_amdgcn_mfma_f32_16x16x32_f16(ah[rs], bh[cs], acc[rs][cs], 0, 0, 0);
                    if (m < 2) {
                        acc[rs][cs] = __builtin_amdgcn_mfma_f32_16x16x32_f16(ah[rs], bl[cs], acc[rs][cs], 0, 0, 0);
                        acc[rs][cs] = __builtin_amdgcn_mfma_f32_16x16x32_f16(al[rs], bh[cs], acc[rs][cs], 0, 0, 0);
                    }
                }
        }
    }

    const int bI = row0 / L_;
    const int rb = row0 - bI * L_;
    f16* sp = (m == 0) ? qsp : ksp;
    #pragma unroll
    for (int rs = 0; rs < 2; ++rs)
        #pragma unroll
        for (int cs = 0; cs < 2; ++cs)
            #pragma unroll
            for (int r = 0; r < 4; ++r) {
                int lrow = r0 + 16 * rs + quad * 4 + r;
                int col  = c0 + 16 * cs + cl;
                float v  = acc[rs][cs][r];
                size_t grow = (size_t)(row0 + lrow);
                if (m < 2) {
                    f16 hv = (f16)v;
                    sp[grow * 128 + col]      = hv;
                    sp[grow * 128 + 64 + col] = (f16)(v - (float)hv);
                } else {
                    vhT[(size_t)(bI * 64 + col) * L_ + rb + lrow] = (f16)v;
                }
            }
}

// ---------------------------------------------------------------------------
// k_dots: mid + edge dots via split-fp16 MFMA; 128x128 tiles; fp16 D/De;
// exact fp32 G sums (two 64-chunks per tile). grid (72, 18) x 256.
// ---------------------------------------------------------------------------
__global__ __launch_bounds__(256) void k_dots(
    const f16* __restrict__ qsp, const f16* __restrict__ ksp,
    f16* __restrict__ D, float* __restrict__ G, f16* __restrict__ De)
{
    const int bx = blockIdx.x, by = blockIdx.y;
    const bool edge = (bx >= 64);
    int b, q0 = 0;
    size_t qrow0;
    if (!edge) {
        if (by >= 17) return;                 // NCOLS = 17 * 128
        b = bx >> 4;
        q0 = (bx * 128) & 2047;
        qrow0 = (size_t)b * L_ + S_ + q0;
    } else {
        int ex = bx - 64;
        b = ex >> 1;
        int half = ex & 1;
        if (half == 0 && by > 0) return;      // start rows see only cols <128
        qrow0 = (size_t)b * L_ + (half ? 2176 : 0);
    }
    const int col0 = by * 128;
    const size_t krow0 = (size_t)b * L_ + col0;

    __shared__ f16 Qs[128 * 136];
    __shared__ f16 Ks[128 * 136];
    const int tid = threadIdx.x;

    #pragma unroll
    for (int i = 0; i < 8; ++i) {
        int g = tid + 256 * i;
        int r = g >> 4, c = g & 15;
        *(uint4*)(Qs + r * 136 + c * 8) = *(const uint4*)(qsp + (qrow0 + r) * 128 + c * 8);
        *(uint4*)(Ks + r * 136 + c * 8) = *(const uint4*)(ksp + (krow0 + r) * 128 + c * 8);
    }
    __syncthreads();

    const int w = tid >> 6, lane = tid & 63;
    const int cl = lane & 15, quad = lane >> 4;

    f32x4 acc[2][8];
    #pragma unroll
    for (int i = 0; i < 2; ++i)
        #pragma unroll
        for (int j = 0; j < 8; ++j) acc[i][j] = 0.f;

    #pragma unroll
    for (int h = 0; h < 2; ++h) {
        half8 ah[2], al[2];
        #pragma unroll
        for (int rs = 0; rs < 2; ++rs) {
            const f16* base = Qs + (32 * w + 16 * rs + cl) * 136 + h * 32 + quad * 8;
            ah[rs] = *(const half8*)(base);
            al[rs] = *(const half8*)(base + 64);
        }
        #pragma unroll
        for (int cq = 0; cq < 2; ++cq) {
            half8 bh[4], bl[4];
            #pragma unroll
            for (int cc = 0; cc < 4; ++cc) {
                const f16* base = Ks + (16 * (cq * 4 + cc) + cl) * 136 + h * 32 + quad * 8;
                bh[cc] = *(const half8*)(base);
                bl[cc] = *(const half8*)(base + 64);
            }
            #pragma unroll
            for (int rs = 0; rs < 2; ++rs)
                #pragma unroll
                for (int cc = 0; cc < 4; ++cc) {
                    int c = cq * 4 + cc;
                    acc[rs][c] = __builtin_amdgcn_mfma_f32_16x16x32_f16(ah[rs], bh[cc], acc[rs][c], 0, 0, 0);
                    acc[rs][c] = __builtin_amdgcn_mfma_f32_16x16x32_f16(ah[rs], bl[cc], acc[rs][c], 0, 0, 0);
                    acc[rs][c] = __builtin_amdgcn_mfma_f32_16x16x32_f16(al[rs], bh[cc], acc[rs][c], 0, 0, 0);
                }
        }
    }

    if (!edge) {
        const int gr0 = bx * 128;
        const bool writeD = (by == 0) || ((by - 1) <= (q0 >> 7));
        if (writeD) {
            #pragma unroll
            for (int rs = 0; rs < 2; ++rs)
                #pragma unroll
                for (int c = 0; c < 8; ++c)
                    #pragma unroll
                    for (int r = 0; r < 4; ++r) {
                        int mrow = gr0 + 32 * w + 16 * rs + quad * 4 + r;
                        int n    = col0 + 16 * c + cl;
                        D[(size_t)mrow * NCOLS + n] = (f16)acc[rs][c][r];
                    }
        }
        if (by >= 1) {
            const int chm = 2 * (by - 1);
            #pragma unroll
            for (int rs = 0; rs < 2; ++rs)
                #pragma unroll
                for (int r = 0; r < 4; ++r) {
                    float sA = 0.f, sB = 0.f;
                    #pragma unroll
                    for (int cc = 0; cc < 4; ++cc) {
                        sA += 1.f / (1.f + __expf(-acc[rs][cc][r]));
                        sB += 1.f / (1.f + __expf(-acc[rs][4 + cc][r]));
                    }
                    #pragma unroll
                    for (int off = 1; off < 16; off <<= 1) {
                        sA += __shfl_xor(sA, off);
                        sB += __shfl_xor(sB, off);
                    }
                    if (cl == 0) {
                        int row = gr0 + 32 * w + 16 * rs + quad * 4 + r;
                        G[(size_t)row * 32 + chm]     = sA;
                        G[(size_t)row * 32 + chm + 1] = sB;
                    }
                }
        }
    } else {
        const int er0 = (bx - 64) * 128;
        #pragma unroll
        for (int rs = 0; rs < 2; ++rs)
            #pragma unroll
            for (int c = 0; c < 8; ++c)
                #pragma unroll
                for (int r = 0; r < 4; ++r) {
                    int erow = er0 + 32 * w + 16 * rs + quad * 4 + r;
                    int n    = col0 + 16 * c + cl;
                    De[(size_t)erow * LE + n] = (f16)acc[rs][c][r];
                }
    }
}

// ---------------------------------------------------------------------------
// k_scan: grid 9216 x 256. (unchanged from round 12 — verified)
// ---------------------------------------------------------------------------
__global__ __launch_bounds__(256) void k_scan(
    const f16* __restrict__ qsp, const float* __restrict__ cope,
    const float* __restrict__ G, f16* __restrict__ D, f16* __restrict__ De)
{
    __shared__ f16   qvh[128];
    __shared__ float li[128];
    __shared__ float Gs[32];
    __shared__ float Gsf[32];
    __shared__ float wmax[4], wsum[4];
    const int tid = threadIdx.x;
    const int gr  = blockIdx.x;
    const int lane = tid & 63, wid = tid >> 6;

    if (gr < NMID) {
        const int b = gr >> 11;
        const int q = gr & 2047;
        const size_t grow = (size_t)b * L_ + S_ + q;
        const int qlim = (q & ~63) + 64;

        if (tid < 16) ((uint4*)qvh)[tid] = ((const uint4*)(qsp + grow * 128))[tid];
        if (tid >= 16 && tid < 24)
            ((float4*)Gs)[tid - 16] = ((const float4*)G)[(size_t)gr * 8 + tid - 16];
        __syncthreads();
        if (tid < 128) {
            float a = 0.f;
            #pragma unroll
            for (int d = 0; d < DK; ++d)
                a += ((float)qvh[d] + (float)qvh[64 + d]) * cope[d * S_ + tid];
            li[tid] = a;
        }
        if (tid >= 128 && tid < 160) {
            int c = tid - 128;
            float s = 0.f;
            for (int cc = c + 1; cc < 32; ++cc) s += Gs[cc];
            Gsf[c] = s;
        }

        f16* Dr = D + (size_t)gr * NCOLS;
        const int j0 = tid * 8;
        const int cg = tid >> 3, sl = tid & 7;
        float dot[8], gte[8];
        float csum = 0.f;
        if (j0 < qlim) {
            U4 t; t.u = *(const uint4*)(Dr + 128 + j0);
            #pragma unroll
            for (int jj = 0; jj < 8; ++jj) {
                dot[jj] = (float)t.h[jj];
                gte[jj] = 1.f / (1.f + __expf(-dot[jj]));
                csum += gte[jj];
            }
        } else {
            #pragma unroll
            for (int jj = 0; jj < 8; ++jj) { dot[jj] = 0.f; gte[jj] = 0.f; }
        }
        float sv = (tid < 128) ? (float)Dr[tid] * SCALE : NEGINF;

        float inc = csum;
        #pragma unroll
        for (int off = 1; off < 8; off <<= 1) {
            float u = __shfl_down(inc, off, 8);
            if (sl + off < 8) inc += u;
        }
        __syncthreads();
        float run = (inc - csum) + Gsf[cg];

        float p8[8];
        #pragma unroll
        for (int jj = 7; jj >= 0; --jj) {
            run += gte[jj];
            float pos = fminf(run, (float)(S_ - 1));
            float pfl = floorf(pos);
            int ic  = (int)ceilf(pos);
            int ifl = (int)pfl;
            float w = pos - pfl;
            float bias = li[ic] * w + li[ifl] * (1.f - w);
            p8[jj] = (j0 + jj <= q) ? dot[jj] * SCALE + bias : NEGINF;
        }

        float mx = sv;
        #pragma unroll
        for (int jj = 0; jj < 8; ++jj) mx = fmaxf(mx, p8[jj]);
        #pragma unroll
        for (int off = 1; off < 64; off <<= 1) mx = fmaxf(mx, __shfl_xor(mx, off));
        if (lane == 0) wmax[wid] = mx;
        __syncthreads();
        mx = fmaxf(fmaxf(wmax[0], wmax[1]), fmaxf(wmax[2], wmax[3]));

        float lsum = 0.f;
        float e8[8];
        #pragma unroll
        for (int jj = 0; jj < 8; ++jj) {
            e8[jj] = __expf(p8[jj] - mx);
            lsum += e8[jj];
        }
        float es = 0.f;
        if (tid < 128) { es = __expf(sv - mx); lsum += es; }
        #pragma unroll
        for (int off = 1; off < 64; off <<= 1) lsum += __shfl_xor(lsum, off);
        if (lane == 0) wsum[wid] = lsum;
        __syncthreads();
        float inv = 1.f / (wsum[0] + wsum[1] + wsum[2] + wsum[3]);

        if (j0 < qlim) {
            U4 o;
            #pragma unroll
            for (int jj = 0; jj < 8; ++jj) o.h[jj] = (f16)(e8[jj] * inv);
            *(uint4*)(Dr + 128 + j0) = o.u;
        }
        if (tid < 128) Dr[tid] = (f16)(es * inv);
    } else {
        const int er = gr - NMID;
        const int r  = er & 255;
        const int Q  = (r < 128) ? r : (2048 + r);
        f16* Er = De + (size_t)er * LE;

        float v[9];
        #pragma unroll
        for (int i = 0; i < 9; ++i) {
            int j = tid + 256 * i;
            float d = (float)Er[j];
            v[i] = (j <= Q) ? d * SCALE : NEGINF;
        }
        float mx = v[0];
        #pragma unroll
        for (int i = 1; i < 9; ++i) mx = fmaxf(mx, v[i]);
        #pragma unroll
        for (int off = 1; off < 64; off <<= 1) mx = fmaxf(mx, __shfl_xor(mx, off));
        if (lane == 0) wmax[wid] = mx;
        __syncthreads();
        mx = fmaxf(fmaxf(wmax[0], wmax[1]), fmaxf(wmax[2], wmax[3]));

        float lsum = 0.f;
        #pragma unroll
        for (int i = 0; i < 9; ++i) {
            v[i] = __expf(v[i] - mx);
            lsum += v[i];
        }
        #pragma unroll
        for (int off = 1; off < 64; off <<= 1) lsum += __shfl_xor(lsum, off);
        if (lane == 0) wsum[wid] = lsum;
        __syncthreads();
        float inv = 1.f / (wsum[0] + wsum[1] + wsum[2] + wsum[3]);

        #pragma unroll
        for (int i = 0; i < 9; ++i)
            Er[tid + 256 * i] = (f16)(v[i] * inv);
    }
}

// ---------------------------------------------------------------------------
// k_pv: mid + edge PV via fp16 MFMA, 4-way K-split, partial stores.
// grid (144, 4) x 256. bx<128: mid. bx>=128: edge.
// ---------------------------------------------------------------------------
__global__ __launch_bounds__(256) void k_pv(
    const f16* __restrict__ Pmid, const f16* __restrict__ Pedge,
    const f16* __restrict__ vhT,
    float* __restrict__ Opart, float* __restrict__ Oe)
{
    __shared__ f16 Ps[64 * 72];
    __shared__ f16 Vt[64 * 72];
    const int tid = threadIdx.x;
    const int bx  = blockIdx.x;
    const int ks  = blockIdx.y;
    const bool edge = (bx >= 128);

    const f16* Pb;
    size_t pitch;
    int row0, b, cap, cmax;
    float* outp;
    if (!edge) {
        row0 = bx * 64;
        b = row0 >> 11;
        int q0 = row0 & 2047;
        Pb = Pmid; pitch = NCOLS; cap = 34;
        cmax = (191 + q0) >> 6;
        outp = Opart + (size_t)ks * NMID * DK;
    } else {
        row0 = (bx - 128) * 64;
        b = row0 >> 8;
        int r0 = row0 & 255;
        Pb = Pedge; pitch = LE; cap = 36;
        int Qmax = (r0 < 128) ? (r0 + 63) : (2048 + r0 + 63);
        cmax = Qmax >> 6;
        outp = Oe + (size_t)ks * NEDGE * DK;
    }
    const int c_beg = ks * 9;
    int c_end = c_beg + 9;
    if (c_end > cap) c_end = cap;
    if (c_end > cmax + 1) c_end = cmax + 1;

    const int w = tid >> 6, lane = tid & 63;
    const int cl = lane & 15, quad = lane >> 4;
    f32x4 acc[4];
    #pragma unroll
    for (int c = 0; c < 4; ++c) acc[c] = 0.f;

    for (int ch = c_beg; ch < c_end; ++ch) {
        __syncthreads();
        #pragma unroll
        for (int i = 0; i < 2; ++i) {
            int g = tid + 256 * i;
            int r = g >> 3, c = g & 7;
            *(uint4*)(Ps + r * 72 + c * 8) =
                *(const uint4*)(Pb + (size_t)(row0 + r) * pitch + ch * 64 + c * 8);
            *(uint4*)(Vt + r * 72 + c * 8) =
                *(const uint4*)(vhT + (size_t)(b * 64 + r) * L_ + ch * 64 + c * 8);
        }
        __syncthreads();
        #pragma unroll
        for (int h = 0; h < 2; ++h) {
            half8 a = *(const half8*)(Ps + (16 * w + cl) * 72 + h * 32 + quad * 8);
            #pragma unroll
            for (int c = 0; c < 4; ++c) {
                half8 bv = *(const half8*)(Vt + (16 * c + cl) * 72 + h * 32 + quad * 8);
                acc[c] = __builtin_amdgcn_mfma_f32_16x16x32_f16(a, bv, acc[c], 0, 0, 0);
            }
        }
    }
    #pragma unroll
    for (int c = 0; c < 4; ++c)
        #pragma unroll
        for (int r = 0; r < 4; ++r) {
            int mrow = row0 + 16 * w + quad * 4 + r;
            int n    = 16 * c + cl;
            outp[(size_t)mrow * DK + n] = acc[c][r];
        }
}

// ---------------------------------------------------------------------------
// k_merge: sum 4 partials, mid + edge. grid 2304 x 256.
// ---------------------------------------------------------------------------
__global__ __launch_bounds__(256) void k_merge(
    const float* __restrict__ Opart, const float* __restrict__ Oe,
    float* __restrict__ out)
{
    const int e = blockIdx.x * 256 + threadIdx.x;
    if (e < NMID * DK) {
        const int gr = e >> 6, c = e & 63;
        const int b  = gr >> 11, q = gr & 2047;
        const int NP = NMID * DK;
        float s = Opart[e] + Opart[e + NP] + Opart[e + 2 * NP] + Opart[e + 3 * NP];
        out[((size_t)b * L_ + S_ + q) * DK + c] = s;
    } else {
        const int e2 = e - NMID * DK;
        const int er = e2 >> 6, c = e2 & 63;
        const int b  = er >> 8, r = er & 255;
        const int gQ = (r < 128) ? r : (2048 + r);
        const int NP = NEDGE * DK;
        float s = Oe[e2] + Oe[e2 + NP] + Oe[e2 + 2 * NP] + Oe[e2 + 3 * NP];
        out[((size_t)b * L_ + gQ) * DK + c] = s;
    }
}

// ---------------------------------------------------------------------------
extern "C" void kernel_launch(void* const* d_in, const int* in_sizes, int n_in,
                              void* d_out, int out_size, void* d_ws, size_t ws_size,
                              hipStream_t stream)
{
    const float* x    = (const float*)d_in[0];
    const float* Wq   = (const float*)d_in[1];
    const float* Wk   = (const float*)d_in[2];
    const float* Wv   = (const float*)d_in[3];
    const float* Wqs  = (const float*)d_in[4];
    const float* Wks  = (const float*)d_in[5];
    const float* Wvs  = (const float*)d_in[6];
    const float* Wqe  = (const float*)d_in[7];
    const float* Wke  = (const float*)d_in[8];
    const float* Wve  = (const float*)d_in[9];
    const float* g0   = (const float*)d_in[10];
    const float* b0   = (const float*)d_in[11];
    const float* gs   = (const float*)d_in[12];
    const float* bs   = (const float*)d_in[13];
    const float* ge   = (const float*)d_in[14];
    const float* be   = (const float*)d_in[15];
    const float* cope = (const float*)d_in[16];

    const size_t NR = (size_t)B_ * L_;               // 9216 rows
    f16*   qsp   = (f16*)d_ws;                       // NR*128 h (hi|lo)
    f16*   ksp   = qsp + NR * 128;                   // NR*128 h
    f16*   vhT   = ksp + NR * 128;                   // NR*64 h
    f16*   Wsp   = vhT + NR * 64;                    // 9*65536 h
    float* G     = (float*)(Wsp + (size_t)9 * 65536); // NMID*32 f32
    float* Opart = G + (size_t)NMID * 32;            // 4*NMID*64 f32
    float* Oe    = Opart + (size_t)4 * NMID * DK;    // 4*NEDGE*64 f32
    f16*   D     = (f16*)(Oe + (size_t)4 * NEDGE * DK); // NMID*NCOLS h
    f16*   De    = D + (size_t)NMID * NCOLS;         // NEDGE*LE h
    float* out   = (float*)d_out;

    k_wsplit<<<dim3(8, 9), 256, 0, stream>>>(Wq, Wk, Wv, Wqs, Wks, Wvs,
                                             Wqe, Wke, Wve, Wsp);
    k_proj<<<dim3(144, 3), 256, 0, stream>>>(x, Wsp, g0, b0, gs, bs, ge, be,
                                             qsp, ksp, vhT);
    k_dots<<<dim3(72, 18), 256, 0, stream>>>(qsp, ksp, D, G, De);
    k_scan<<<NMID + NEDGE, 256, 0, stream>>>(qsp, cope, G, D, De);
    k_pv  <<<dim3(144, 4), 256, 0, stream>>>(D, De, vhT, Opart, Oe);
    k_merge<<<(NMID + NEDGE) * DK / 256, 256, 0, stream>>>(Opart, Oe, out);
}